// Round 1
// baseline (8063.152 us; speedup 1.0000x reference)
//
#include <hip/hip_runtime.h>
#include <hip/hip_bf16.h>
#include <cstdint>

#define NTOK 4096
#define HID  2048
#define ITER 768
#define NEXP 64
#define TOPK 8

typedef __attribute__((ext_vector_type(8))) short sh8;
typedef __attribute__((ext_vector_type(4))) float f32x4;

#define MFMA16 __builtin_amdgcn_mfma_f32_16x16x32_bf16

__device__ __forceinline__ uint16_t f2b(float f) {
  union { float f; uint32_t u; } v; v.f = f;
  uint32_t u = v.u;
  u += 0x7FFFu + ((u >> 16) & 1u);   // RNE
  return (uint16_t)(u >> 16);
}

// ---------------- zero out + histogram state ----------------
__global__ __launch_bounds__(256) void zero_kernel(float* __restrict__ out,
                                                   int* __restrict__ cc) {
  size_t i = (size_t)blockIdx.x * 256 + threadIdx.x;
  float4 z = {0.f, 0.f, 0.f, 0.f};
  *(float4*)(out + i * 4) = z;
  if (i < 128) cc[(int)i] = 0;   // counts[64] + cursor[64]
}

// ---------------- x fp32 -> bf16 ----------------
__global__ __launch_bounds__(256) void xcast_kernel(const float* __restrict__ x,
                                                    uint16_t* __restrict__ xb) {
  size_t i = ((size_t)blockIdx.x * 256 + threadIdx.x) * 8;
  float4 a = *(const float4*)(x + i);
  float4 b = *(const float4*)(x + i + 4);
  uint4 o;
  o.x = (uint32_t)f2b(a.x) | ((uint32_t)f2b(a.y) << 16);
  o.y = (uint32_t)f2b(a.z) | ((uint32_t)f2b(a.w) << 16);
  o.z = (uint32_t)f2b(b.x) | ((uint32_t)f2b(b.y) << 16);
  o.w = (uint32_t)f2b(b.z) | ((uint32_t)f2b(b.w) << 16);
  *(uint4*)(xb + i) = o;
}

// ---------------- router: logits + top8 + softmax + histogram ----------------
__global__ __launch_bounds__(256) void router_kernel(
    const float* __restrict__ x, const float* __restrict__ gate_w,
    float* __restrict__ logits, int* __restrict__ topk_id,
    float* __restrict__ topk_w, int* __restrict__ counts)
{
  int lane = threadIdx.x & 63;
  int wv   = threadIdx.x >> 6;
  int t    = blockIdx.x * 4 + wv;
  const float* xr = x + (size_t)t * HID;
  float acc = 0.f;
  #pragma unroll 4
  for (int h = 0; h < HID; h += 4) {
    float4 xv = *(const float4*)(xr + h);
    acc += xv.x * gate_w[(h + 0) * NEXP + lane];
    acc += xv.y * gate_w[(h + 1) * NEXP + lane];
    acc += xv.z * gate_w[(h + 2) * NEXP + lane];
    acc += xv.w * gate_w[(h + 3) * NEXP + lane];
  }
  logits[(size_t)t * NEXP + lane] = acc;

  float v = acc;
  float topv[TOPK]; int topi[TOPK];
  #pragma unroll
  for (int k = 0; k < TOPK; ++k) {
    float bv = v; int bi = lane;
    #pragma unroll
    for (int off = 32; off > 0; off >>= 1) {
      float ov = __shfl_xor(bv, off);
      int   oi = __shfl_xor(bi, off);
      if (ov > bv || (ov == bv && oi < bi)) { bv = ov; bi = oi; }
    }
    topv[k] = bv; topi[k] = bi;
    if (lane == bi) v = -3.0e38f;
  }
  float m = topv[0], s = 0.f, w[TOPK];
  #pragma unroll
  for (int k = 0; k < TOPK; ++k) { w[k] = __expf(topv[k] - m); s += w[k]; }
  float inv = 1.f / s;
  if (lane < TOPK) {
    topk_id[t * TOPK + lane] = topi[lane];
    topk_w[t * TOPK + lane]  = w[lane] * inv;
    atomicAdd(&counts[topi[lane]], 1);
  }
}

// ---------------- offsets (exclusive scan over 64 counts) ----------------
__global__ void offsets_kernel(const int* __restrict__ counts, int* __restrict__ offsets) {
  if (threadIdx.x == 0) {
    int s = 0;
    for (int e = 0; e < NEXP; ++e) { offsets[e] = s; s += counts[e]; }
    offsets[NEXP] = s;
  }
}

// ---------------- scatter pairs grouped by expert ----------------
__global__ __launch_bounds__(256) void scatter_kernel(
    const int* __restrict__ topk_id, const float* __restrict__ topk_w,
    const int* __restrict__ offsets, int* __restrict__ cursor,
    int* __restrict__ pair_tok, float* __restrict__ pair_w)
{
  int p = blockIdx.x * 256 + threadIdx.x;   // pair index = t*8+k
  int e = topk_id[p];
  int pos = offsets[e] + atomicAdd(&cursor[e], 1);
  pair_tok[pos] = p;
  pair_w[pos]   = topk_w[p];
}

// ---------------- staged transposed weight tile: W[k][n] fp32 -> bT[n][40] bf16 ----------------
__device__ __forceinline__ void stage_bT(const float* __restrict__ W, int ldw,
                                         int k0, int n0, uint16_t* bT) {
  const int t  = threadIdx.x;
  const int n  = t & 127;
  const int kb = (t >> 7) * 8;
  const float* Wp = W + (size_t)k0 * ldw + n0 + n;
  #pragma unroll
  for (int pass = 0; pass < 2; ++pass) {
    int k8 = kb + pass * 16;
    uint32_t pk[4];
    #pragma unroll
    for (int q = 0; q < 4; ++q) {
      float w0 = Wp[(size_t)(k8 + 2 * q) * ldw];
      float w1 = Wp[(size_t)(k8 + 2 * q + 1) * ldw];
      pk[q] = (uint32_t)f2b(w0) | ((uint32_t)f2b(w1) << 16);
    }
    uint4 o; o.x = pk[0]; o.y = pk[1]; o.z = pk[2]; o.w = pk[3];
    *(uint4*)&bT[n * 40 + k8] = o;
  }
}

// ---------------- fused expert pipeline: gate/up GEMM -> silu*up -> down GEMM -> atomic out ----------------
__global__ __launch_bounds__(256) void moe_kernel(
    const uint16_t* __restrict__ xb,
    const float* __restrict__ gate_proj,
    const float* __restrict__ up_proj,
    const float* __restrict__ down_proj,
    const int* __restrict__ pair_tok,
    const float* __restrict__ pair_w,
    const int* __restrict__ offsets,
    float* __restrict__ out)
{
  const int e     = blockIdx.y;
  const int start = offsets[e];
  const int count = offsets[e + 1] - start;
  const int row0  = blockIdx.x * 64;
  if (row0 >= count) return;
  const int nvalid = min(64, count - row0);

  __shared__ __align__(16) uint16_t a_tile[64 * 40];
  __shared__ __align__(16) uint16_t bT0[128 * 40];
  __shared__ __align__(16) uint16_t bT1[128 * 40];
  __shared__ __align__(16) uint16_t act[64 * 776];   // 768 + 8 pad
  __shared__ int   s_tok[64];
  __shared__ float s_w[64];

  const int t = threadIdx.x;
  if (t < 64) {
    int tok = 0; float w = 0.f;
    if (t < nvalid) {
      int p = pair_tok[start + row0 + t];
      tok = p >> 3;
      w   = pair_w[start + row0 + t];
    }
    s_tok[t] = tok; s_w[t] = w;
  }
  __syncthreads();

  const int rowA = t >> 2, koffA = (t & 3) * 8;
  const size_t xrow = (size_t)s_tok[rowA] * HID;

  const int lane = t & 63;
  const int wv = t >> 6, wr = wv >> 1, wc = wv & 1;
  const int lr = lane & 15, lg = lane >> 4;

  const float* Wg = gate_proj + (size_t)e * HID * ITER;
  const float* Wu = up_proj   + (size_t)e * HID * ITER;
  const float* Wd = down_proj + (size_t)e * ITER * HID;

  // ---------- phase 1: act = silu(x*Wg) .* (x*Wu), over 6 N-chunks of 128 ----------
  for (int nc = 0; nc < 6; ++nc) {
    f32x4 accg[2][4], accu[2][4];
    #pragma unroll
    for (int mi = 0; mi < 2; ++mi)
      #pragma unroll
      for (int ni = 0; ni < 4; ++ni) {
        accg[mi][ni] = (f32x4){0.f, 0.f, 0.f, 0.f};
        accu[mi][ni] = (f32x4){0.f, 0.f, 0.f, 0.f};
      }
    for (int kc = 0; kc < 64; ++kc) {
      __syncthreads();
      *(uint4*)&a_tile[rowA * 40 + koffA] =
          *(const uint4*)&xb[xrow + (size_t)kc * 32 + koffA];
      stage_bT(Wg, ITER, kc * 32, nc * 128, bT0);
      stage_bT(Wu, ITER, kc * 32, nc * 128, bT1);
      __syncthreads();
      sh8 af0 = *(const sh8*)&a_tile[(wr * 32 +  0 + lr) * 40 + lg * 8];
      sh8 af1 = *(const sh8*)&a_tile[(wr * 32 + 16 + lr) * 40 + lg * 8];
      #pragma unroll
      for (int ni = 0; ni < 4; ++ni) {
        int col = wc * 64 + ni * 16 + lr;
        sh8 bg = *(const sh8*)&bT0[col * 40 + lg * 8];
        sh8 bu = *(const sh8*)&bT1[col * 40 + lg * 8];
        accg[0][ni] = MFMA16(af0, bg, accg[0][ni], 0, 0, 0);
        accg[1][ni] = MFMA16(af1, bg, accg[1][ni], 0, 0, 0);
        accu[0][ni] = MFMA16(af0, bu, accu[0][ni], 0, 0, 0);
        accu[1][ni] = MFMA16(af1, bu, accu[1][ni], 0, 0, 0);
      }
    }
    #pragma unroll
    for (int mi = 0; mi < 2; ++mi)
      #pragma unroll
      for (int ni = 0; ni < 4; ++ni)
        #pragma unroll
        for (int j = 0; j < 4; ++j) {
          float g = accg[mi][ni][j], u = accu[mi][ni][j];
          float a = (g / (1.f + __expf(-g))) * u;
          int row = wr * 32 + mi * 16 + lg * 4 + j;
          int col = nc * 128 + wc * 64 + ni * 16 + lr;
          act[row * 776 + col] = f2b(a);
        }
  }

  // ---------- phase 2: out += w * (act * Wd), over 16 N-chunks of 128 ----------
  for (int nc = 0; nc < 16; ++nc) {
    f32x4 acc[2][4];
    #pragma unroll
    for (int mi = 0; mi < 2; ++mi)
      #pragma unroll
      for (int ni = 0; ni < 4; ++ni)
        acc[mi][ni] = (f32x4){0.f, 0.f, 0.f, 0.f};
    for (int kc = 0; kc < 24; ++kc) {
      __syncthreads();
      stage_bT(Wd, HID, kc * 32, nc * 128, bT0);
      __syncthreads();
      sh8 af0 = *(const sh8*)&act[(wr * 32 +  0 + lr) * 776 + kc * 32 + lg * 8];
      sh8 af1 = *(const sh8*)&act[(wr * 32 + 16 + lr) * 776 + kc * 32 + lg * 8];
      #pragma unroll
      for (int ni = 0; ni < 4; ++ni) {
        int col = wc * 64 + ni * 16 + lr;
        sh8 bd = *(const sh8*)&bT0[col * 40 + lg * 8];
        acc[0][ni] = MFMA16(af0, bd, acc[0][ni], 0, 0, 0);
        acc[1][ni] = MFMA16(af1, bd, acc[1][ni], 0, 0, 0);
      }
    }
    #pragma unroll
    for (int mi = 0; mi < 2; ++mi)
      #pragma unroll
      for (int ni = 0; ni < 4; ++ni)
        #pragma unroll
        for (int j = 0; j < 4; ++j) {
          int row = wr * 32 + mi * 16 + lg * 4 + j;
          if (row < nvalid) {
            int col = nc * 128 + wc * 64 + ni * 16 + lr;
            atomicAdd(&out[(size_t)s_tok[row] * HID + col],
                      s_w[row] * acc[mi][ni][j]);
          }
        }
  }
}

extern "C" void kernel_launch(void* const* d_in, const int* in_sizes, int n_in,
                              void* d_out, int out_size, void* d_ws, size_t ws_size,
                              hipStream_t stream) {
  const float* x         = (const float*)d_in[0];
  const float* gate_w    = (const float*)d_in[1];
  const float* gate_proj = (const float*)d_in[2];
  const float* up_proj   = (const float*)d_in[3];
  const float* down_proj = (const float*)d_in[4];

  float* out    = (float*)d_out;                     // [4096, 2048]
  float* logits = out + (size_t)NTOK * HID;          // [4096, 64]

  // workspace layout (~17.3 MB total)
  char* ws = (char*)d_ws;
  uint16_t* xb      = (uint16_t*)ws;                  // 16,777,216 B
  int*      topk_id = (int*)  (ws + 16777216);        //    131,072 B
  float*    topk_w  = (float*)(ws + 16908288);        //    131,072 B
  int*      counts  = (int*)  (ws + 17039360);        //        256 B
  int*      cursor  = (int*)  (ws + 17039616);        //        256 B (contiguous with counts)
  int*      offsets = (int*)  (ws + 17039872);        //        272 B
  int*      pair_tok= (int*)  (ws + 17040144);        //    131,072 B
  float*    pair_w  = (float*)(ws + 17171216);        //    131,072 B

  zero_kernel   <<<8192, 256, 0, stream>>>(out, counts);
  xcast_kernel  <<<4096, 256, 0, stream>>>(x, xb);
  router_kernel <<<1024, 256, 0, stream>>>(x, gate_w, logits, topk_id, topk_w, counts);
  offsets_kernel<<<1,    64,  0, stream>>>(counts, offsets);
  scatter_kernel<<<128,  256, 0, stream>>>(topk_id, topk_w, offsets, cursor, pair_tok, pair_w);
  moe_kernel    <<<dim3(64, 64), 256, 0, stream>>>(xb, gate_proj, up_proj, down_proj,
                                                   pair_tok, pair_w, offsets, out);
}

// Round 2
// 4634.088 us; speedup vs baseline: 1.7400x; 1.7400x over previous
//
#include <hip/hip_runtime.h>
#include <hip/hip_bf16.h>
#include <cstdint>

#define NTOK 4096
#define HID  2048
#define ITER 768
#define NEXP 64
#define TOPK 8

typedef __attribute__((ext_vector_type(8))) short sh8;
typedef __attribute__((ext_vector_type(4))) float f32x4;

#define MFMA16 __builtin_amdgcn_mfma_f32_16x16x32_bf16

__device__ __forceinline__ uint16_t f2b(float f) {
  union { float f; uint32_t u; } v; v.f = f;
  uint32_t u = v.u;
  u += 0x7FFFu + ((u >> 16) & 1u);   // RNE
  return (uint16_t)(u >> 16);
}

// ---------------- zero out + histogram state ----------------
__global__ __launch_bounds__(256) void zero_kernel(float* __restrict__ out,
                                                   int* __restrict__ cc) {
  size_t i = (size_t)blockIdx.x * 256 + threadIdx.x;
  float4 z = {0.f, 0.f, 0.f, 0.f};
  *(float4*)(out + i * 4) = z;
  if (i < 128) cc[(int)i] = 0;   // counts[64] + cursor[64]
}

// ---------------- x fp32 -> bf16 ----------------
__global__ __launch_bounds__(256) void xcast_kernel(const float* __restrict__ x,
                                                    uint16_t* __restrict__ xb) {
  size_t i = ((size_t)blockIdx.x * 256 + threadIdx.x) * 8;
  float4 a = *(const float4*)(x + i);
  float4 b = *(const float4*)(x + i + 4);
  uint4 o;
  o.x = (uint32_t)f2b(a.x) | ((uint32_t)f2b(a.y) << 16);
  o.y = (uint32_t)f2b(a.z) | ((uint32_t)f2b(a.w) << 16);
  o.z = (uint32_t)f2b(b.x) | ((uint32_t)f2b(b.y) << 16);
  o.w = (uint32_t)f2b(b.z) | ((uint32_t)f2b(b.w) << 16);
  *(uint4*)(xb + i) = o;
}

// ---------------- router: logits + top8 + softmax + histogram ----------------
__global__ __launch_bounds__(256) void router_kernel(
    const float* __restrict__ x, const float* __restrict__ gate_w,
    float* __restrict__ logits, int* __restrict__ topk_id,
    float* __restrict__ topk_w, int* __restrict__ counts)
{
  int lane = threadIdx.x & 63;
  int wv   = threadIdx.x >> 6;
  int t    = blockIdx.x * 4 + wv;
  const float* xr = x + (size_t)t * HID;
  float acc = 0.f;
  #pragma unroll 4
  for (int h = 0; h < HID; h += 4) {
    float4 xv = *(const float4*)(xr + h);
    acc += xv.x * gate_w[(h + 0) * NEXP + lane];
    acc += xv.y * gate_w[(h + 1) * NEXP + lane];
    acc += xv.z * gate_w[(h + 2) * NEXP + lane];
    acc += xv.w * gate_w[(h + 3) * NEXP + lane];
  }
  logits[(size_t)t * NEXP + lane] = acc;

  float v = acc;
  float topv[TOPK]; int topi[TOPK];
  #pragma unroll
  for (int k = 0; k < TOPK; ++k) {
    float bv = v; int bi = lane;
    #pragma unroll
    for (int off = 32; off > 0; off >>= 1) {
      float ov = __shfl_xor(bv, off);
      int   oi = __shfl_xor(bi, off);
      if (ov > bv || (ov == bv && oi < bi)) { bv = ov; bi = oi; }
    }
    topv[k] = bv; topi[k] = bi;
    if (lane == bi) v = -3.0e38f;
  }
  float m = topv[0], s = 0.f, w[TOPK];
  #pragma unroll
  for (int k = 0; k < TOPK; ++k) { w[k] = __expf(topv[k] - m); s += w[k]; }
  float inv = 1.f / s;
  if (lane < TOPK) {
    topk_id[t * TOPK + lane] = topi[lane];
    topk_w[t * TOPK + lane]  = w[lane] * inv;
    atomicAdd(&counts[topi[lane]], 1);
  }
}

// ---------------- offsets (exclusive scan over 64 counts) ----------------
__global__ void offsets_kernel(const int* __restrict__ counts, int* __restrict__ offsets) {
  if (threadIdx.x == 0) {
    int s = 0;
    for (int e = 0; e < NEXP; ++e) { offsets[e] = s; s += counts[e]; }
    offsets[NEXP] = s;
  }
}

// ---------------- scatter pairs grouped by expert ----------------
__global__ __launch_bounds__(256) void scatter_kernel(
    const int* __restrict__ topk_id, const float* __restrict__ topk_w,
    const int* __restrict__ offsets, int* __restrict__ cursor,
    int* __restrict__ pair_tok, float* __restrict__ pair_w)
{
  int p = blockIdx.x * 256 + threadIdx.x;   // pair index = t*8+k
  int e = topk_id[p];
  int pos = offsets[e] + atomicAdd(&cursor[e], 1);
  pair_tok[pos] = p;
  pair_w[pos]   = topk_w[p];
}

// ================= gate/up grouped GEMM -> act (bf16) =================
// grid (32 row-tiles, 6 n-chunks, 64 experts), 256 threads (4 waves 2x2)
__global__ __launch_bounds__(256, 2) void gateup_kernel(
    const uint16_t* __restrict__ xb,
    const float* __restrict__ gate_proj,
    const float* __restrict__ up_proj,
    const int* __restrict__ pair_tok,
    const int* __restrict__ offsets,
    uint16_t* __restrict__ act)
{
  const int e     = blockIdx.z;
  const int nc    = blockIdx.y;
  const int start = offsets[e];
  const int count = offsets[e + 1] - start;
  const int row0  = blockIdx.x * 128;
  if (row0 >= count) return;
  const int nvalid = min(128, count - row0);

  __shared__ __align__(16) uint16_t aT[128 * 40];
  __shared__ __align__(16) uint16_t bg[128 * 40];
  __shared__ __align__(16) uint16_t bu[128 * 40];
  __shared__ int s_tok[128];

  const int t = threadIdx.x;
  if (t < 128) {
    int tok = 0;
    if (t < nvalid) tok = pair_tok[start + row0 + t] >> 3;
    s_tok[t] = tok;
  }
  __syncthreads();

  const int arow = t >> 1, aseg = (t & 1) * 16;
  const uint16_t* xsrc = xb + (size_t)s_tok[arow] * HID + aseg;

  const int bn = t & 127, bk0 = (t >> 7) * 16;
  const float* Wg = gate_proj + (size_t)e * HID * ITER + (size_t)bk0 * ITER + nc * 128 + bn;
  const float* Wu = up_proj   + (size_t)e * HID * ITER + (size_t)bk0 * ITER + nc * 128 + bn;

  const int lane = t & 63, wv = t >> 6, wr = wv >> 1, wc = wv & 1;
  const int lr = lane & 15, hi = lane >> 4;

  f32x4 accg[4][4], accu[4][4];
  #pragma unroll
  for (int mi = 0; mi < 4; ++mi)
    #pragma unroll
    for (int ni = 0; ni < 4; ++ni) {
      accg[mi][ni] = (f32x4){0.f, 0.f, 0.f, 0.f};
      accu[mi][ni] = (f32x4){0.f, 0.f, 0.f, 0.f};
    }

  for (int kc = 0; kc < 64; ++kc) {
    __syncthreads();
    // A tile: 128 rows x 32 k, bf16, layout [row][40]
    {
      const uint16_t* xs = xsrc + kc * 32;
      uint4 a0 = *(const uint4*)xs;
      uint4 a1 = *(const uint4*)(xs + 8);
      *(uint4*)&aT[arow * 40 + aseg]     = a0;
      *(uint4*)&aT[arow * 40 + aseg + 8] = a1;
    }
    // B tiles: coalesced fp32 row reads (lane = consecutive n), cvt, transposed LDS write
    {
      const float* wg = Wg + (size_t)(kc * 32) * ITER;
      uint32_t pk[8];
      #pragma unroll
      for (int q = 0; q < 8; ++q) {
        float w0 = wg[(size_t)(2 * q) * ITER];
        float w1 = wg[(size_t)(2 * q + 1) * ITER];
        pk[q] = (uint32_t)f2b(w0) | ((uint32_t)f2b(w1) << 16);
      }
      uint4 o0 = {pk[0], pk[1], pk[2], pk[3]}, o1 = {pk[4], pk[5], pk[6], pk[7]};
      *(uint4*)&bg[bn * 40 + bk0]     = o0;
      *(uint4*)&bg[bn * 40 + bk0 + 8] = o1;
    }
    {
      const float* wu = Wu + (size_t)(kc * 32) * ITER;
      uint32_t pk[8];
      #pragma unroll
      for (int q = 0; q < 8; ++q) {
        float w0 = wu[(size_t)(2 * q) * ITER];
        float w1 = wu[(size_t)(2 * q + 1) * ITER];
        pk[q] = (uint32_t)f2b(w0) | ((uint32_t)f2b(w1) << 16);
      }
      uint4 o0 = {pk[0], pk[1], pk[2], pk[3]}, o1 = {pk[4], pk[5], pk[6], pk[7]};
      *(uint4*)&bu[bn * 40 + bk0]     = o0;
      *(uint4*)&bu[bn * 40 + bk0 + 8] = o1;
    }
    __syncthreads();

    sh8 af[4];
    #pragma unroll
    for (int mi = 0; mi < 4; ++mi)
      af[mi] = *(const sh8*)&aT[(wr * 64 + mi * 16 + lr) * 40 + hi * 8];
    #pragma unroll
    for (int ni = 0; ni < 4; ++ni) {
      sh8 bgf = *(const sh8*)&bg[(wc * 64 + ni * 16 + lr) * 40 + hi * 8];
      sh8 buf_ = *(const sh8*)&bu[(wc * 64 + ni * 16 + lr) * 40 + hi * 8];
      #pragma unroll
      for (int mi = 0; mi < 4; ++mi) {
        accg[mi][ni] = MFMA16(af[mi], bgf, accg[mi][ni], 0, 0, 0);
        accu[mi][ni] = MFMA16(af[mi], buf_, accu[mi][ni], 0, 0, 0);
      }
    }
  }

  // epilogue: silu(g)*u -> bf16 act (rows grouped by expert)
  #pragma unroll
  for (int mi = 0; mi < 4; ++mi)
    #pragma unroll
    for (int ni = 0; ni < 4; ++ni)
      #pragma unroll
      for (int j = 0; j < 4; ++j) {
        int row = wr * 64 + mi * 16 + hi * 4 + j;
        if (row < nvalid) {
          int col = nc * 128 + wc * 64 + ni * 16 + lr;
          float g = accg[mi][ni][j], u = accu[mi][ni][j];
          float a = (g / (1.f + __expf(-g))) * u;
          act[(size_t)(start + row0 + row) * ITER + col] = f2b(a);
        }
      }
}

// ================= down grouped GEMM -> atomic scatter to out =================
// grid (32 row-tiles, 16 n-chunks, 64 experts), 256 threads (4 waves 2x2)
__global__ __launch_bounds__(256, 2) void down_kernel(
    const uint16_t* __restrict__ act,
    const float* __restrict__ down_proj,
    const int* __restrict__ pair_tok,
    const float* __restrict__ pair_w,
    const int* __restrict__ offsets,
    float* __restrict__ out)
{
  const int e     = blockIdx.z;
  const int nc    = blockIdx.y;
  const int start = offsets[e];
  const int count = offsets[e + 1] - start;
  const int row0  = blockIdx.x * 128;
  if (row0 >= count) return;
  const int nvalid = min(128, count - row0);

  __shared__ __align__(16) uint16_t aT[128 * 40];
  __shared__ __align__(16) uint16_t bd[128 * 40];
  __shared__ int   s_tok[128];
  __shared__ float s_w[128];

  const int t = threadIdx.x;
  if (t < 128) {
    int tok = 0; float w = 0.f;
    if (t < nvalid) {
      tok = pair_tok[start + row0 + t] >> 3;
      w   = pair_w[start + row0 + t];
    }
    s_tok[t] = tok; s_w[t] = w;
  }
  __syncthreads();

  const int arow = t >> 1, aseg = (t & 1) * 16;
  const uint16_t* asrc = act + (size_t)(start + row0 + arow) * ITER + aseg;

  const int bn = t & 127, bk0 = (t >> 7) * 16;
  const float* Wd = down_proj + (size_t)e * ITER * HID + (size_t)bk0 * HID + nc * 128 + bn;

  const int lane = t & 63, wv = t >> 6, wr = wv >> 1, wc = wv & 1;
  const int lr = lane & 15, hi = lane >> 4;

  f32x4 acc[4][4];
  #pragma unroll
  for (int mi = 0; mi < 4; ++mi)
    #pragma unroll
    for (int ni = 0; ni < 4; ++ni)
      acc[mi][ni] = (f32x4){0.f, 0.f, 0.f, 0.f};

  for (int kc = 0; kc < 24; ++kc) {
    __syncthreads();
    {
      const uint16_t* as = asrc + kc * 32;
      uint4 a0 = *(const uint4*)as;
      uint4 a1 = *(const uint4*)(as + 8);
      *(uint4*)&aT[arow * 40 + aseg]     = a0;
      *(uint4*)&aT[arow * 40 + aseg + 8] = a1;
    }
    {
      const float* wd = Wd + (size_t)(kc * 32) * HID;
      uint32_t pk[8];
      #pragma unroll
      for (int q = 0; q < 8; ++q) {
        float w0 = wd[(size_t)(2 * q) * HID];
        float w1 = wd[(size_t)(2 * q + 1) * HID];
        pk[q] = (uint32_t)f2b(w0) | ((uint32_t)f2b(w1) << 16);
      }
      uint4 o0 = {pk[0], pk[1], pk[2], pk[3]}, o1 = {pk[4], pk[5], pk[6], pk[7]};
      *(uint4*)&bd[bn * 40 + bk0]     = o0;
      *(uint4*)&bd[bn * 40 + bk0 + 8] = o1;
    }
    __syncthreads();

    sh8 af[4];
    #pragma unroll
    for (int mi = 0; mi < 4; ++mi)
      af[mi] = *(const sh8*)&aT[(wr * 64 + mi * 16 + lr) * 40 + hi * 8];
    #pragma unroll
    for (int ni = 0; ni < 4; ++ni) {
      sh8 bdf = *(const sh8*)&bd[(wc * 64 + ni * 16 + lr) * 40 + hi * 8];
      #pragma unroll
      for (int mi = 0; mi < 4; ++mi)
        acc[mi][ni] = MFMA16(af[mi], bdf, acc[mi][ni], 0, 0, 0);
    }
  }

  #pragma unroll
  for (int mi = 0; mi < 4; ++mi)
    #pragma unroll
    for (int ni = 0; ni < 4; ++ni)
      #pragma unroll
      for (int j = 0; j < 4; ++j) {
        int row = wr * 64 + mi * 16 + hi * 4 + j;
        if (row < nvalid) {
          int col = nc * 128 + wc * 64 + ni * 16 + lr;
          atomicAdd(&out[(size_t)s_tok[row] * HID + col],
                    s_w[row] * acc[mi][ni][j]);
        }
      }
}

extern "C" void kernel_launch(void* const* d_in, const int* in_sizes, int n_in,
                              void* d_out, int out_size, void* d_ws, size_t ws_size,
                              hipStream_t stream) {
  const float* x         = (const float*)d_in[0];
  const float* gate_w    = (const float*)d_in[1];
  const float* gate_proj = (const float*)d_in[2];
  const float* up_proj   = (const float*)d_in[3];
  const float* down_proj = (const float*)d_in[4];

  float* out    = (float*)d_out;                     // [4096, 2048]
  float* logits = out + (size_t)NTOK * HID;          // [4096, 64]

  // workspace layout (~67.9 MB total)
  char* ws = (char*)d_ws;
  uint16_t* xb      = (uint16_t*)ws;                  // 16,777,216 B
  uint16_t* act     = (uint16_t*)(ws + 16777216);     // 32896*768*2 = 50,528,256 B (128-row pad)
  int*      topk_id = (int*)  (ws + 67305472);        //    131,072 B
  float*    topk_w  = (float*)(ws + 67436544);        //    131,072 B
  int*      counts  = (int*)  (ws + 67567616);        //        256 B
  int*      cursor  = (int*)  (ws + 67567872);        //        256 B
  int*      offsets = (int*)  (ws + 67568128);        //        384 B
  int*      pair_tok= (int*)  (ws + 67568512);        //    131,072 B
  float*    pair_w  = (float*)(ws + 67699584);        //    131,072 B

  zero_kernel   <<<8192, 256, 0, stream>>>(out, counts);
  xcast_kernel  <<<4096, 256, 0, stream>>>(x, xb);
  router_kernel <<<1024, 256, 0, stream>>>(x, gate_w, logits, topk_id, topk_w, counts);
  offsets_kernel<<<1,    64,  0, stream>>>(counts, offsets);
  scatter_kernel<<<128,  256, 0, stream>>>(topk_id, topk_w, offsets, cursor, pair_tok, pair_w);
  gateup_kernel <<<dim3(32, 6, 64),  256, 0, stream>>>(xb, gate_proj, up_proj,
                                                       pair_tok, offsets, act);
  down_kernel   <<<dim3(32, 16, 64), 256, 0, stream>>>(act, down_proj,
                                                       pair_tok, pair_w, offsets, out);
}

// Round 3
// 3292.186 us; speedup vs baseline: 2.4492x; 1.4076x over previous
//
#include <hip/hip_runtime.h>
#include <hip/hip_bf16.h>
#include <cstdint>

#define NTOK 4096
#define HID  2048
#define ITER 768
#define NEXP 64
#define TOPK 8

typedef __attribute__((ext_vector_type(8))) short sh8;
typedef __attribute__((ext_vector_type(4))) float f32x4;

#define MFMA16 __builtin_amdgcn_mfma_f32_16x16x32_bf16

__device__ __forceinline__ uint16_t f2b(float f) {
  union { float f; uint32_t u; } v; v.f = f;
  uint32_t u = v.u;
  u += 0x7FFFu + ((u >> 16) & 1u);   // RNE
  return (uint16_t)(u >> 16);
}

__device__ __forceinline__ void gl2lds16(const void* g, void* l) {
  __builtin_amdgcn_global_load_lds(
      (const __attribute__((address_space(1))) uint32_t*)g,
      (__attribute__((address_space(3))) uint32_t*)l, 16, 0, 0);
}

// ---------------- zero out + histogram state ----------------
__global__ __launch_bounds__(256) void zero_kernel(float* __restrict__ out,
                                                   int* __restrict__ cc) {
  size_t i = (size_t)blockIdx.x * 256 + threadIdx.x;
  float4 z = {0.f, 0.f, 0.f, 0.f};
  *(float4*)(out + i * 4) = z;
  if (i < 128) cc[(int)i] = 0;   // counts[64] + cursor[64]
}

// ---------------- x fp32 -> bf16 ----------------
__global__ __launch_bounds__(256) void xcast_kernel(const float* __restrict__ x,
                                                    uint16_t* __restrict__ xb) {
  size_t i = ((size_t)blockIdx.x * 256 + threadIdx.x) * 8;
  float4 a = *(const float4*)(x + i);
  float4 b = *(const float4*)(x + i + 4);
  uint4 o;
  o.x = (uint32_t)f2b(a.x) | ((uint32_t)f2b(a.y) << 16);
  o.y = (uint32_t)f2b(a.z) | ((uint32_t)f2b(a.w) << 16);
  o.z = (uint32_t)f2b(b.x) | ((uint32_t)f2b(b.y) << 16);
  o.w = (uint32_t)f2b(b.z) | ((uint32_t)f2b(b.w) << 16);
  *(uint4*)(xb + i) = o;
}

// ---------------- weight prep: fp32 [K][N] -> bf16 [r(n)][K] ----------------
// mode 0: r=n    (down_proj)
// mode 1: r=((n>>4)<<5)+(n&15)      (gate cols -> even 16-blocks of combined)
// mode 2: r=((n>>4)<<5)+16+(n&15)   (up cols   -> odd 16-blocks)
__global__ __launch_bounds__(256) void wprep_kernel(
    const float* __restrict__ src, uint16_t* __restrict__ dst,
    int K, int N, int R, int mode)
{
  const int e  = blockIdx.z;
  const int k8 = blockIdx.x * 32 + (threadIdx.x >> 6) * 8;
  const int nl = threadIdx.x & 63;
  const float* sp = src + (size_t)e * K * N + (size_t)k8 * N;
  uint16_t* dp = dst + (size_t)e * R * K;
  for (int nn = 0; nn < 4; ++nn) {
    int n = blockIdx.y * 256 + nn * 64 + nl;
    float v[8];
    #pragma unroll
    for (int j = 0; j < 8; ++j) v[j] = sp[(size_t)j * N + n];
    uint4 o;
    o.x = (uint32_t)f2b(v[0]) | ((uint32_t)f2b(v[1]) << 16);
    o.y = (uint32_t)f2b(v[2]) | ((uint32_t)f2b(v[3]) << 16);
    o.z = (uint32_t)f2b(v[4]) | ((uint32_t)f2b(v[5]) << 16);
    o.w = (uint32_t)f2b(v[6]) | ((uint32_t)f2b(v[7]) << 16);
    int r = (mode == 0) ? n : (((n >> 4) << 5) + (n & 15) + ((mode == 2) ? 16 : 0));
    *(uint4*)&dp[(size_t)r * K + k8] = o;
  }
}

// ---------------- router: logits + top8 + softmax + histogram ----------------
__global__ __launch_bounds__(256) void router_kernel(
    const float* __restrict__ x, const float* __restrict__ gate_w,
    float* __restrict__ logits, int* __restrict__ topk_id,
    float* __restrict__ topk_w, int* __restrict__ counts)
{
  int lane = threadIdx.x & 63;
  int wv   = threadIdx.x >> 6;
  int t    = blockIdx.x * 4 + wv;
  const float* xr = x + (size_t)t * HID;
  float acc = 0.f;
  #pragma unroll 4
  for (int h = 0; h < HID; h += 4) {
    float4 xv = *(const float4*)(xr + h);
    acc += xv.x * gate_w[(h + 0) * NEXP + lane];
    acc += xv.y * gate_w[(h + 1) * NEXP + lane];
    acc += xv.z * gate_w[(h + 2) * NEXP + lane];
    acc += xv.w * gate_w[(h + 3) * NEXP + lane];
  }
  logits[(size_t)t * NEXP + lane] = acc;

  float v = acc;
  float topv[TOPK]; int topi[TOPK];
  #pragma unroll
  for (int k = 0; k < TOPK; ++k) {
    float bv = v; int bi = lane;
    #pragma unroll
    for (int off = 32; off > 0; off >>= 1) {
      float ov = __shfl_xor(bv, off);
      int   oi = __shfl_xor(bi, off);
      if (ov > bv || (ov == bv && oi < bi)) { bv = ov; bi = oi; }
    }
    topv[k] = bv; topi[k] = bi;
    if (lane == bi) v = -3.0e38f;
  }
  float m = topv[0], s = 0.f, w[TOPK];
  #pragma unroll
  for (int k = 0; k < TOPK; ++k) { w[k] = __expf(topv[k] - m); s += w[k]; }
  float inv = 1.f / s;
  if (lane < TOPK) {
    topk_id[t * TOPK + lane] = topi[lane];
    topk_w[t * TOPK + lane]  = w[lane] * inv;
    atomicAdd(&counts[topi[lane]], 1);
  }
}

// ---------------- offsets (exclusive scan over 64 counts) ----------------
__global__ void offsets_kernel(const int* __restrict__ counts, int* __restrict__ offsets) {
  if (threadIdx.x == 0) {
    int s = 0;
    for (int e = 0; e < NEXP; ++e) { offsets[e] = s; s += counts[e]; }
    offsets[NEXP] = s;
  }
}

// ---------------- scatter pairs grouped by expert ----------------
__global__ __launch_bounds__(256) void scatter_kernel(
    const int* __restrict__ topk_id, const float* __restrict__ topk_w,
    const int* __restrict__ offsets, int* __restrict__ cursor,
    int* __restrict__ pair_tok, float* __restrict__ pair_w)
{
  int p = blockIdx.x * 256 + threadIdx.x;   // pair index = t*8+k
  int e = topk_id[p];
  int pos = offsets[e] + atomicAdd(&cursor[e], 1);
  pair_tok[pos] = p;
  pair_w[pos]   = topk_w[p];
}

// ================= gate+up grouped GEMM (combined interleaved N=1536) =================
// grid (32 row-tiles, 12 n-chunks, 64 experts), 256 threads (4 waves 2x2)
__global__ __launch_bounds__(256, 2) void gateup_kernel(
    const uint16_t* __restrict__ xb,
    const uint16_t* __restrict__ gu_t,     // [e][1536][2048] bf16, 16-row gate/up interleave
    const int* __restrict__ pair_tok,
    const int* __restrict__ offsets,
    uint16_t* __restrict__ act)
{
  const int e     = blockIdx.z;
  const int nc    = blockIdx.y;
  const int start = offsets[e];
  const int count = offsets[e + 1] - start;
  const int row0  = blockIdx.x * 128;
  if (row0 >= count) return;
  const int nvalid = min(128, count - row0);

  __shared__ __align__(16) uint16_t aT[128 * 64];
  __shared__ __align__(16) uint16_t bT[128 * 64];
  __shared__ int s_tok[128];

  const int t = threadIdx.x, l = t & 63, w = t >> 6;
  if (t < 128)
    s_tok[t] = (t < nvalid) ? (pair_tok[start + row0 + t] >> 3) : 0;
  __syncthreads();

  const int sub = l >> 3;                       // row-in-8-group
  const int xk  = ((l & 7) ^ sub) << 3;         // swizzled source k-chunk (elements)

  const uint16_t* srcA[4]; const uint16_t* srcB[4];
  char* dstA[4]; char* dstB[4];
  const uint16_t* gub = gu_t + (size_t)e * 1536 * HID;
  #pragma unroll
  for (int q = 0; q < 4; ++q) {
    int rl = (w * 4 + q) * 8 + sub;
    srcA[q] = xb + (size_t)s_tok[rl] * HID + xk;
    srcB[q] = gub + (size_t)(nc * 128 + rl) * HID + xk;
    dstA[q] = (char*)aT + (w * 4 + q) * 1024;
    dstB[q] = (char*)bT + (w * 4 + q) * 1024;
  }

  const int wr = w >> 1, wc = w & 1, lr = l & 15, hi = l >> 4;
  const int xorv = (lr & 7) << 4;               // byte XOR for swizzled read

  f32x4 acc[4][4];
  #pragma unroll
  for (int mi = 0; mi < 4; ++mi)
    #pragma unroll
    for (int ni = 0; ni < 4; ++ni)
      acc[mi][ni] = (f32x4){0.f, 0.f, 0.f, 0.f};

  for (int kc = 0; kc < 32; ++kc) {
    __syncthreads();
    #pragma unroll
    for (int q = 0; q < 4; ++q) {
      gl2lds16(srcA[q] + kc * 64, dstA[q]);
      gl2lds16(srcB[q] + kc * 64, dstB[q]);
    }
    __syncthreads();
    #pragma unroll
    for (int ks = 0; ks < 2; ++ks) {
      sh8 af[4], bf[4];
      #pragma unroll
      for (int mi = 0; mi < 4; ++mi)
        af[mi] = *(const sh8*)((const char*)aT +
                   (wr * 64 + mi * 16 + lr) * 128 + ((ks * 64 + hi * 16) ^ xorv));
      #pragma unroll
      for (int ni = 0; ni < 4; ++ni)
        bf[ni] = *(const sh8*)((const char*)bT +
                   (wc * 64 + ni * 16 + lr) * 128 + ((ks * 64 + hi * 16) ^ xorv));
      #pragma unroll
      for (int mi = 0; mi < 4; ++mi)
        #pragma unroll
        for (int ni = 0; ni < 4; ++ni)
          acc[mi][ni] = MFMA16(af[mi], bf[ni], acc[mi][ni], 0, 0, 0);
    }
  }

  // epilogue: ni even = gate, ni odd = up (same original column) -> silu(g)*u
  #pragma unroll
  for (int mi = 0; mi < 4; ++mi)
    #pragma unroll
    for (int p = 0; p < 2; ++p)
      #pragma unroll
      for (int j = 0; j < 4; ++j) {
        int row = wr * 64 + mi * 16 + hi * 4 + j;
        if (row < nvalid) {
          float g = acc[mi][2 * p][j], u = acc[mi][2 * p + 1][j];
          float a = (g / (1.f + __expf(-g))) * u;
          int col = nc * 64 + wc * 32 + p * 16 + lr;
          act[(size_t)(start + row0 + row) * ITER + col] = f2b(a);
        }
      }
}

// ================= down grouped GEMM -> weighted atomic scatter =================
// grid (32 row-tiles, 16 n-chunks, 64 experts), 256 threads (4 waves 2x2)
__global__ __launch_bounds__(256, 2) void down_kernel(
    const uint16_t* __restrict__ act,
    const uint16_t* __restrict__ down_t,   // [e][2048][768] bf16
    const int* __restrict__ pair_tok,
    const float* __restrict__ pair_w,
    const int* __restrict__ offsets,
    float* __restrict__ out)
{
  const int e     = blockIdx.z;
  const int nc    = blockIdx.y;
  const int start = offsets[e];
  const int count = offsets[e + 1] - start;
  const int row0  = blockIdx.x * 128;
  if (row0 >= count) return;
  const int nvalid = min(128, count - row0);

  __shared__ __align__(16) uint16_t aT[128 * 64];
  __shared__ __align__(16) uint16_t bT[128 * 64];
  __shared__ int   s_tok[128];
  __shared__ float s_w[128];

  const int t = threadIdx.x, l = t & 63, w = t >> 6;
  if (t < 128) {
    int tok = 0; float wt = 0.f;
    if (t < nvalid) {
      tok = pair_tok[start + row0 + t] >> 3;
      wt  = pair_w[start + row0 + t];
    }
    s_tok[t] = tok; s_w[t] = wt;
  }
  __syncthreads();

  const int sub = l >> 3;
  const int xk  = ((l & 7) ^ sub) << 3;

  const uint16_t* srcA[4]; const uint16_t* srcB[4];
  char* dstA[4]; char* dstB[4];
  const uint16_t* wdb = down_t + (size_t)e * HID * ITER;
  #pragma unroll
  for (int q = 0; q < 4; ++q) {
    int rl = (w * 4 + q) * 8 + sub;
    srcA[q] = act + (size_t)(start + row0 + rl) * ITER + xk;
    srcB[q] = wdb + (size_t)(nc * 128 + rl) * ITER + xk;
    dstA[q] = (char*)aT + (w * 4 + q) * 1024;
    dstB[q] = (char*)bT + (w * 4 + q) * 1024;
  }

  const int wr = w >> 1, wc = w & 1, lr = l & 15, hi = l >> 4;
  const int xorv = (lr & 7) << 4;

  f32x4 acc[4][4];
  #pragma unroll
  for (int mi = 0; mi < 4; ++mi)
    #pragma unroll
    for (int ni = 0; ni < 4; ++ni)
      acc[mi][ni] = (f32x4){0.f, 0.f, 0.f, 0.f};

  for (int kc = 0; kc < 12; ++kc) {
    __syncthreads();
    #pragma unroll
    for (int q = 0; q < 4; ++q) {
      gl2lds16(srcA[q] + kc * 64, dstA[q]);
      gl2lds16(srcB[q] + kc * 64, dstB[q]);
    }
    __syncthreads();
    #pragma unroll
    for (int ks = 0; ks < 2; ++ks) {
      sh8 af[4], bf[4];
      #pragma unroll
      for (int mi = 0; mi < 4; ++mi)
        af[mi] = *(const sh8*)((const char*)aT +
                   (wr * 64 + mi * 16 + lr) * 128 + ((ks * 64 + hi * 16) ^ xorv));
      #pragma unroll
      for (int ni = 0; ni < 4; ++ni)
        bf[ni] = *(const sh8*)((const char*)bT +
                   (wc * 64 + ni * 16 + lr) * 128 + ((ks * 64 + hi * 16) ^ xorv));
      #pragma unroll
      for (int mi = 0; mi < 4; ++mi)
        #pragma unroll
        for (int ni = 0; ni < 4; ++ni)
          acc[mi][ni] = MFMA16(af[mi], bf[ni], acc[mi][ni], 0, 0, 0);
    }
  }

  #pragma unroll
  for (int mi = 0; mi < 4; ++mi)
    #pragma unroll
    for (int ni = 0; ni < 4; ++ni)
      #pragma unroll
      for (int j = 0; j < 4; ++j) {
        int row = wr * 64 + mi * 16 + hi * 4 + j;
        if (row < nvalid) {
          int col = nc * 128 + wc * 64 + ni * 16 + lr;
          atomicAdd(&out[(size_t)s_tok[row] * HID + col],
                    s_w[row] * acc[mi][ni][j]);
        }
      }
}

extern "C" void kernel_launch(void* const* d_in, const int* in_sizes, int n_in,
                              void* d_out, int out_size, void* d_ws, size_t ws_size,
                              hipStream_t stream) {
  const float* x         = (const float*)d_in[0];
  const float* gate_w    = (const float*)d_in[1];
  const float* gate_proj = (const float*)d_in[2];
  const float* up_proj   = (const float*)d_in[3];
  const float* down_proj = (const float*)d_in[4];

  float* out    = (float*)d_out;                     // [4096, 2048]
  float* logits = out + (size_t)NTOK * HID;          // [4096, 64]

  // workspace layout (~672 MB total)
  char* ws = (char*)d_ws;
  size_t off = 0;
  uint16_t* xb      = (uint16_t*)(ws + off); off += (size_t)NTOK * HID * 2;            // 16.8 MB
  uint16_t* gu_t    = (uint16_t*)(ws + off); off += (size_t)NEXP * 1536 * HID * 2;     // 402.7 MB
  uint16_t* down_t  = (uint16_t*)(ws + off); off += (size_t)NEXP * HID * ITER * 2;     // 201.3 MB
  uint16_t* act     = (uint16_t*)(ws + off); off += (size_t)(NTOK * TOPK + 128) * ITER * 2; // 50.5 MB
  int*      topk_id = (int*)  (ws + off); off += (size_t)NTOK * TOPK * 4;
  float*    topk_w  = (float*)(ws + off); off += (size_t)NTOK * TOPK * 4;
  int*      counts  = (int*)  (ws + off); off += 256;
  int*      cursor  = (int*)  (ws + off); off += 256;
  int*      offsets = (int*)  (ws + off); off += 512;
  int*      pair_tok= (int*)  (ws + off); off += (size_t)NTOK * TOPK * 4;
  float*    pair_w  = (float*)(ws + off); off += (size_t)NTOK * TOPK * 4;

  zero_kernel   <<<8192, 256, 0, stream>>>(out, counts);
  xcast_kernel  <<<4096, 256, 0, stream>>>(x, xb);
  router_kernel <<<1024, 256, 0, stream>>>(x, gate_w, logits, topk_id, topk_w, counts);
  offsets_kernel<<<1,    64,  0, stream>>>(counts, offsets);
  scatter_kernel<<<128,  256, 0, stream>>>(topk_id, topk_w, offsets, cursor, pair_tok, pair_w);

  // weight prep: fp32 [K][N] -> bf16 [n][K] (gate/up interleaved into gu_t)
  wprep_kernel<<<dim3(64, 3, 64), 256, 0, stream>>>(gate_proj, gu_t,   HID,  ITER, 1536, 1);
  wprep_kernel<<<dim3(64, 3, 64), 256, 0, stream>>>(up_proj,   gu_t,   HID,  ITER, 1536, 2);
  wprep_kernel<<<dim3(24, 8, 64), 256, 0, stream>>>(down_proj, down_t, ITER, HID,  HID,  0);

  gateup_kernel<<<dim3(32, 12, 64), 256, 0, stream>>>(xb, gu_t, pair_tok, offsets, act);
  down_kernel  <<<dim3(32, 16, 64), 256, 0, stream>>>(act, down_t, pair_tok, pair_w, offsets, out);
}

// Round 4
// 1433.374 us; speedup vs baseline: 5.6253x; 2.2968x over previous
//
#include <hip/hip_runtime.h>
#include <hip/hip_bf16.h>
#include <cstdint>

#define NTOK 4096
#define HID  2048
#define ITER 768
#define NEXP 64
#define TOPK 8
#define MAXT 320   // max row-tiles: 32768/128 + 63 padding tiles

typedef __attribute__((ext_vector_type(8))) short sh8;
typedef __attribute__((ext_vector_type(4))) float f32x4;

#define MFMA16 __builtin_amdgcn_mfma_f32_16x16x32_bf16

__device__ __forceinline__ uint16_t f2b(float f) {
  union { float f; uint32_t u; } v; v.f = f;
  uint32_t u = v.u;
  u += 0x7FFFu + ((u >> 16) & 1u);   // RNE
  return (uint16_t)(u >> 16);
}

__device__ __forceinline__ void gl2lds16(const void* g, void* l) {
  __builtin_amdgcn_global_load_lds(
      (const __attribute__((address_space(1))) uint32_t*)g,
      (__attribute__((address_space(3))) uint32_t*)l, 16, 0, 0);
}

// m204 bijective XCD-chunked swizzle: hw slot s -> logical L (contiguous L per XCD)
__device__ __forceinline__ int xcd_unswizzle(int s, int na) {
  int q = na >> 3, r = na & 7, x = s & 7, i = s >> 3;
  return (x < r ? x * (q + 1) : r * (q + 1) + (x - r) * q) + i;
}

// ---------------- zero out + histogram state ----------------
__global__ __launch_bounds__(256) void zero_kernel(float* __restrict__ out,
                                                   int* __restrict__ cc) {
  size_t i = (size_t)blockIdx.x * 256 + threadIdx.x;
  float4 z = {0.f, 0.f, 0.f, 0.f};
  *(float4*)(out + i * 4) = z;
  if (i < 128) cc[(int)i] = 0;   // counts[64] + cursor[64]
}

// ---------------- x fp32 -> bf16 ----------------
__global__ __launch_bounds__(256) void xcast_kernel(const float* __restrict__ x,
                                                    uint16_t* __restrict__ xb) {
  size_t i = ((size_t)blockIdx.x * 256 + threadIdx.x) * 8;
  float4 a = *(const float4*)(x + i);
  float4 b = *(const float4*)(x + i + 4);
  uint4 o;
  o.x = (uint32_t)f2b(a.x) | ((uint32_t)f2b(a.y) << 16);
  o.y = (uint32_t)f2b(a.z) | ((uint32_t)f2b(a.w) << 16);
  o.z = (uint32_t)f2b(b.x) | ((uint32_t)f2b(b.y) << 16);
  o.w = (uint32_t)f2b(b.z) | ((uint32_t)f2b(b.w) << 16);
  *(uint4*)(xb + i) = o;
}

// ---------------- weight prep: fp32 [K][N] -> bf16 [r(n)][K] ----------------
// mode 0: r=n ; mode 1: r=((n>>4)<<5)+(n&15) ; mode 2: r=((n>>4)<<5)+16+(n&15)
__global__ __launch_bounds__(256) void wprep_kernel(
    const float* __restrict__ src, uint16_t* __restrict__ dst,
    int K, int N, int R, int mode)
{
  const int e  = blockIdx.z;
  const int k8 = blockIdx.x * 32 + (threadIdx.x >> 6) * 8;
  const int nl = threadIdx.x & 63;
  const float* sp = src + (size_t)e * K * N + (size_t)k8 * N;
  uint16_t* dp = dst + (size_t)e * R * K;
  for (int nn = 0; nn < 4; ++nn) {
    int n = blockIdx.y * 256 + nn * 64 + nl;
    float v[8];
    #pragma unroll
    for (int j = 0; j < 8; ++j) v[j] = sp[(size_t)j * N + n];
    uint4 o;
    o.x = (uint32_t)f2b(v[0]) | ((uint32_t)f2b(v[1]) << 16);
    o.y = (uint32_t)f2b(v[2]) | ((uint32_t)f2b(v[3]) << 16);
    o.z = (uint32_t)f2b(v[4]) | ((uint32_t)f2b(v[5]) << 16);
    o.w = (uint32_t)f2b(v[6]) | ((uint32_t)f2b(v[7]) << 16);
    int r = (mode == 0) ? n : (((n >> 4) << 5) + (n & 15) + ((mode == 2) ? 16 : 0));
    *(uint4*)&dp[(size_t)r * K + k8] = o;
  }
}

// ---------------- router: logits + top8 + softmax + histogram ----------------
__global__ __launch_bounds__(256) void router_kernel(
    const float* __restrict__ x, const float* __restrict__ gate_w,
    float* __restrict__ logits, int* __restrict__ topk_id,
    float* __restrict__ topk_w, int* __restrict__ counts)
{
  int lane = threadIdx.x & 63;
  int wv   = threadIdx.x >> 6;
  int t    = blockIdx.x * 4 + wv;
  const float* xr = x + (size_t)t * HID;
  float acc = 0.f;
  #pragma unroll 4
  for (int h = 0; h < HID; h += 4) {
    float4 xv = *(const float4*)(xr + h);
    acc += xv.x * gate_w[(h + 0) * NEXP + lane];
    acc += xv.y * gate_w[(h + 1) * NEXP + lane];
    acc += xv.z * gate_w[(h + 2) * NEXP + lane];
    acc += xv.w * gate_w[(h + 3) * NEXP + lane];
  }
  logits[(size_t)t * NEXP + lane] = acc;

  float v = acc;
  float topv[TOPK]; int topi[TOPK];
  #pragma unroll
  for (int k = 0; k < TOPK; ++k) {
    float bv = v; int bi = lane;
    #pragma unroll
    for (int off = 32; off > 0; off >>= 1) {
      float ov = __shfl_xor(bv, off);
      int   oi = __shfl_xor(bi, off);
      if (ov > bv || (ov == bv && oi < bi)) { bv = ov; bi = oi; }
    }
    topv[k] = bv; topi[k] = bi;
    if (lane == bi) v = -3.0e38f;
  }
  float m = topv[0], s = 0.f, w[TOPK];
  #pragma unroll
  for (int k = 0; k < TOPK; ++k) { w[k] = __expf(topv[k] - m); s += w[k]; }
  float inv = 1.f / s;
  if (lane < TOPK) {
    topk_id[t * TOPK + lane] = topi[lane];
    topk_w[t * TOPK + lane]  = w[lane] * inv;
    atomicAdd(&counts[topi[lane]], 1);
  }
}

// ---------------- offsets + dense tile list ----------------
__global__ void offsets_kernel(const int* __restrict__ counts, int* __restrict__ offsets,
                               int* __restrict__ tiles, int* __restrict__ tilecount) {
  if (threadIdx.x == 0) {
    int s = 0, nt = 0;
    for (int e = 0; e < NEXP; ++e) {
      offsets[e] = s;
      int c = counts[e];
      for (int rb = 0; rb * 128 < c; ++rb) tiles[nt++] = (e << 16) | rb;
      s += c;
    }
    offsets[NEXP] = s;
    tilecount[0] = nt;
  }
}

// ---------------- scatter pairs grouped by expert ----------------
__global__ __launch_bounds__(256) void scatter_kernel(
    const int* __restrict__ topk_id, const float* __restrict__ topk_w,
    const int* __restrict__ offsets, int* __restrict__ cursor,
    int* __restrict__ pair_tok, float* __restrict__ pair_w)
{
  int p = blockIdx.x * 256 + threadIdx.x;   // pair index = t*8+k
  int e = topk_id[p];
  int pos = offsets[e] + atomicAdd(&cursor[e], 1);
  pair_tok[pos] = p;
  pair_w[pos]   = topk_w[p];
}

// ================= gate+up grouped GEMM (combined interleaved N=1536) =================
// 1D grid MAXT*12, tile-list driven, XCD-balanced
__global__ __launch_bounds__(256, 2) void gateup_kernel(
    const uint16_t* __restrict__ xb,
    const uint16_t* __restrict__ gu_t,     // [e][1536][2048] bf16, 16-row gate/up interleave
    const int* __restrict__ pair_tok,
    const int* __restrict__ offsets,
    const int* __restrict__ tiles,
    const int* __restrict__ tilecount,
    uint16_t* __restrict__ act)
{
  const int nt = tilecount[0];
  const int na = nt * 12;
  if (blockIdx.x >= na) return;
  const int L  = xcd_unswizzle(blockIdx.x, na);
  const int ti = L % nt, nc = L / nt;
  const int te = tiles[ti];
  const int e = te >> 16, row0 = (te & 0xffff) * 128;
  const int start = offsets[e];
  const int count = offsets[e + 1] - start;
  const int nvalid = min(128, count - row0);

  __shared__ __align__(16) uint16_t aT[128 * 64];
  __shared__ __align__(16) uint16_t bT[128 * 64];
  __shared__ int s_tok[128];

  const int t = threadIdx.x, l = t & 63, w = t >> 6;
  if (t < 128)
    s_tok[t] = (t < nvalid) ? (pair_tok[start + row0 + t] >> 3) : 0;
  __syncthreads();

  const int sub = l >> 3;                       // row-in-8-group
  const int xk  = ((l & 7) ^ sub) << 3;         // swizzled source k-chunk (elements)

  const uint16_t* srcA[4]; const uint16_t* srcB[4];
  char* dstA[4]; char* dstB[4];
  const uint16_t* gub = gu_t + (size_t)e * 1536 * HID;
  #pragma unroll
  for (int q = 0; q < 4; ++q) {
    int rl = (w * 4 + q) * 8 + sub;
    srcA[q] = xb + (size_t)s_tok[rl] * HID + xk;
    srcB[q] = gub + (size_t)(nc * 128 + rl) * HID + xk;
    dstA[q] = (char*)aT + (w * 4 + q) * 1024;
    dstB[q] = (char*)bT + (w * 4 + q) * 1024;
  }

  const int wr = w >> 1, wc = w & 1, lr = l & 15, hi = l >> 4;
  const int xorv = (lr & 7) << 4;               // byte XOR for swizzled read

  f32x4 acc[4][4];
  #pragma unroll
  for (int mi = 0; mi < 4; ++mi)
    #pragma unroll
    for (int ni = 0; ni < 4; ++ni)
      acc[mi][ni] = (f32x4){0.f, 0.f, 0.f, 0.f};

  for (int kc = 0; kc < 32; ++kc) {
    __syncthreads();
    #pragma unroll
    for (int q = 0; q < 4; ++q) {
      gl2lds16(srcA[q] + kc * 64, dstA[q]);
      gl2lds16(srcB[q] + kc * 64, dstB[q]);
    }
    __syncthreads();
    #pragma unroll
    for (int ks = 0; ks < 2; ++ks) {
      sh8 af[4], bf[4];
      #pragma unroll
      for (int mi = 0; mi < 4; ++mi)
        af[mi] = *(const sh8*)((const char*)aT +
                   (wr * 64 + mi * 16 + lr) * 128 + ((ks * 64 + hi * 16) ^ xorv));
      #pragma unroll
      for (int ni = 0; ni < 4; ++ni)
        bf[ni] = *(const sh8*)((const char*)bT +
                   (wc * 64 + ni * 16 + lr) * 128 + ((ks * 64 + hi * 16) ^ xorv));
      #pragma unroll
      for (int mi = 0; mi < 4; ++mi)
        #pragma unroll
        for (int ni = 0; ni < 4; ++ni)
          acc[mi][ni] = MFMA16(af[mi], bf[ni], acc[mi][ni], 0, 0, 0);
    }
  }

  // epilogue: ni even = gate, ni odd = up (same original column) -> silu(g)*u
  #pragma unroll
  for (int mi = 0; mi < 4; ++mi)
    #pragma unroll
    for (int p = 0; p < 2; ++p)
      #pragma unroll
      for (int j = 0; j < 4; ++j) {
        int row = wr * 64 + mi * 16 + hi * 4 + j;
        if (row < nvalid) {
          float g = acc[mi][2 * p][j], u = acc[mi][2 * p + 1][j];
          float a = (g / (1.f + __expf(-g))) * u;
          int col = nc * 64 + wc * 32 + p * 16 + lr;
          act[(size_t)(start + row0 + row) * ITER + col] = f2b(a);
        }
      }
}

// ================= down grouped GEMM -> weighted atomic scatter =================
// 1D grid MAXT*16, tile-list driven, XCD-balanced
__global__ __launch_bounds__(256, 2) void down_kernel(
    const uint16_t* __restrict__ act,
    const uint16_t* __restrict__ down_t,   // [e][2048][768] bf16
    const int* __restrict__ pair_tok,
    const float* __restrict__ pair_w,
    const int* __restrict__ offsets,
    const int* __restrict__ tiles,
    const int* __restrict__ tilecount,
    float* __restrict__ out)
{
  const int nt = tilecount[0];
  const int na = nt * 16;
  if (blockIdx.x >= na) return;
  const int L  = xcd_unswizzle(blockIdx.x, na);
  const int ti = L % nt, nc = L / nt;
  const int te = tiles[ti];
  const int e = te >> 16, row0 = (te & 0xffff) * 128;
  const int start = offsets[e];
  const int count = offsets[e + 1] - start;
  const int nvalid = min(128, count - row0);

  __shared__ __align__(16) uint16_t aT[128 * 64];
  __shared__ __align__(16) uint16_t bT[128 * 64];
  __shared__ int   s_tok[128];
  __shared__ float s_w[128];

  const int t = threadIdx.x, l = t & 63, w = t >> 6;
  if (t < 128) {
    int tok = 0; float wt = 0.f;
    if (t < nvalid) {
      tok = pair_tok[start + row0 + t] >> 3;
      wt  = pair_w[start + row0 + t];
    }
    s_tok[t] = tok; s_w[t] = wt;
  }
  __syncthreads();

  const int sub = l >> 3;
  const int xk  = ((l & 7) ^ sub) << 3;

  const uint16_t* srcA[4]; const uint16_t* srcB[4];
  char* dstA[4]; char* dstB[4];
  const uint16_t* wdb = down_t + (size_t)e * HID * ITER;
  #pragma unroll
  for (int q = 0; q < 4; ++q) {
    int rl = (w * 4 + q) * 8 + sub;
    srcA[q] = act + (size_t)(start + row0 + rl) * ITER + xk;
    srcB[q] = wdb + (size_t)(nc * 128 + rl) * ITER + xk;
    dstA[q] = (char*)aT + (w * 4 + q) * 1024;
    dstB[q] = (char*)bT + (w * 4 + q) * 1024;
  }

  const int wr = w >> 1, wc = w & 1, lr = l & 15, hi = l >> 4;
  const int xorv = (lr & 7) << 4;

  f32x4 acc[4][4];
  #pragma unroll
  for (int mi = 0; mi < 4; ++mi)
    #pragma unroll
    for (int ni = 0; ni < 4; ++ni)
      acc[mi][ni] = (f32x4){0.f, 0.f, 0.f, 0.f};

  for (int kc = 0; kc < 12; ++kc) {
    __syncthreads();
    #pragma unroll
    for (int q = 0; q < 4; ++q) {
      gl2lds16(srcA[q] + kc * 64, dstA[q]);
      gl2lds16(srcB[q] + kc * 64, dstB[q]);
    }
    __syncthreads();
    #pragma unroll
    for (int ks = 0; ks < 2; ++ks) {
      sh8 af[4], bf[4];
      #pragma unroll
      for (int mi = 0; mi < 4; ++mi)
        af[mi] = *(const sh8*)((const char*)aT +
                   (wr * 64 + mi * 16 + lr) * 128 + ((ks * 64 + hi * 16) ^ xorv));
      #pragma unroll
      for (int ni = 0; ni < 4; ++ni)
        bf[ni] = *(const sh8*)((const char*)bT +
                   (wc * 64 + ni * 16 + lr) * 128 + ((ks * 64 + hi * 16) ^ xorv));
      #pragma unroll
      for (int mi = 0; mi < 4; ++mi)
        #pragma unroll
        for (int ni = 0; ni < 4; ++ni)
          acc[mi][ni] = MFMA16(af[mi], bf[ni], acc[mi][ni], 0, 0, 0);
    }
  }

  #pragma unroll
  for (int mi = 0; mi < 4; ++mi)
    #pragma unroll
    for (int ni = 0; ni < 4; ++ni)
      #pragma unroll
      for (int j = 0; j < 4; ++j) {
        int row = wr * 64 + mi * 16 + hi * 4 + j;
        if (row < nvalid) {
          int col = nc * 128 + wc * 64 + ni * 16 + lr;
          atomicAdd(&out[(size_t)s_tok[row] * HID + col],
                    s_w[row] * acc[mi][ni][j]);
        }
      }
}

extern "C" void kernel_launch(void* const* d_in, const int* in_sizes, int n_in,
                              void* d_out, int out_size, void* d_ws, size_t ws_size,
                              hipStream_t stream) {
  const float* x         = (const float*)d_in[0];
  const float* gate_w    = (const float*)d_in[1];
  const float* gate_proj = (const float*)d_in[2];
  const float* up_proj   = (const float*)d_in[3];
  const float* down_proj = (const float*)d_in[4];

  float* out    = (float*)d_out;                     // [4096, 2048]
  float* logits = out + (size_t)NTOK * HID;          // [4096, 64]

  // workspace layout (~672 MB total)
  char* ws = (char*)d_ws;
  size_t off = 0;
  uint16_t* xb      = (uint16_t*)(ws + off); off += (size_t)NTOK * HID * 2;            // 16.8 MB
  uint16_t* gu_t    = (uint16_t*)(ws + off); off += (size_t)NEXP * 1536 * HID * 2;     // 402.7 MB
  uint16_t* down_t  = (uint16_t*)(ws + off); off += (size_t)NEXP * HID * ITER * 2;     // 201.3 MB
  uint16_t* act     = (uint16_t*)(ws + off); off += (size_t)(NTOK * TOPK + 128) * ITER * 2; // 50.5 MB
  int*      topk_id = (int*)  (ws + off); off += (size_t)NTOK * TOPK * 4;
  float*    topk_w  = (float*)(ws + off); off += (size_t)NTOK * TOPK * 4;
  int*      counts  = (int*)  (ws + off); off += 256;
  int*      cursor  = (int*)  (ws + off); off += 256;
  int*      offsets = (int*)  (ws + off); off += 512;
  int*      tiles   = (int*)  (ws + off); off += MAXT * 4;
  int*      tilecount=(int*)  (ws + off); off += 256;
  int*      pair_tok= (int*)  (ws + off); off += (size_t)NTOK * TOPK * 4;
  float*    pair_w  = (float*)(ws + off); off += (size_t)NTOK * TOPK * 4;

  zero_kernel   <<<8192, 256, 0, stream>>>(out, counts);
  xcast_kernel  <<<4096, 256, 0, stream>>>(x, xb);
  router_kernel <<<1024, 256, 0, stream>>>(x, gate_w, logits, topk_id, topk_w, counts);
  offsets_kernel<<<1,    64,  0, stream>>>(counts, offsets, tiles, tilecount);
  scatter_kernel<<<128,  256, 0, stream>>>(topk_id, topk_w, offsets, cursor, pair_tok, pair_w);

  // weight prep: fp32 [K][N] -> bf16 [n][K] (gate/up interleaved into gu_t)
  wprep_kernel<<<dim3(64, 3, 64), 256, 0, stream>>>(gate_proj, gu_t,   HID,  ITER, 1536, 1);
  wprep_kernel<<<dim3(64, 3, 64), 256, 0, stream>>>(up_proj,   gu_t,   HID,  ITER, 1536, 2);
  wprep_kernel<<<dim3(24, 8, 64), 256, 0, stream>>>(down_proj, down_t, ITER, HID,  HID,  0);

  gateup_kernel<<<MAXT * 12, 256, 0, stream>>>(xb, gu_t, pair_tok, offsets,
                                               tiles, tilecount, act);
  down_kernel  <<<MAXT * 16, 256, 0, stream>>>(act, down_t, pair_tok, pair_w, offsets,
                                               tiles, tilecount, out);
}

// Round 5
// 1062.138 us; speedup vs baseline: 7.5914x; 1.3495x over previous
//
#include <hip/hip_runtime.h>
#include <hip/hip_bf16.h>
#include <cstdint>

#define NTOK 4096
#define HID  2048
#define ITER 768
#define NEXP 64
#define TOPK 8
#define MAXT 320   // max row-tiles: 32768/128 + 63 padding tiles

typedef __attribute__((ext_vector_type(8))) short sh8;
typedef __attribute__((ext_vector_type(4))) float f32x4;

#define MFMA16 __builtin_amdgcn_mfma_f32_16x16x32_bf16

__device__ __forceinline__ uint16_t f2b(float f) {
  union { float f; uint32_t u; } v; v.f = f;
  uint32_t u = v.u;
  u += 0x7FFFu + ((u >> 16) & 1u);   // RNE
  return (uint16_t)(u >> 16);
}

__device__ __forceinline__ float b2f_lo(uint32_t w) {   // bf16 in bits[15:0]
  union { uint32_t u; float f; } v; v.u = w << 16; return v.f;
}
__device__ __forceinline__ float b2f_hi(uint32_t w) {   // bf16 in bits[31:16]
  union { uint32_t u; float f; } v; v.u = w & 0xffff0000u; return v.f;
}

__device__ __forceinline__ void gl2lds16(const void* g, void* l) {
  __builtin_amdgcn_global_load_lds(
      (const __attribute__((address_space(1))) uint32_t*)g,
      (__attribute__((address_space(3))) uint32_t*)l, 16, 0, 0);
}

// m204 bijective XCD-chunked swizzle: hw slot s -> logical L (contiguous L per XCD)
__device__ __forceinline__ int xcd_unswizzle(int s, int na) {
  int q = na >> 3, r = na & 7, x = s & 7, i = s >> 3;
  return (x < r ? x * (q + 1) : r * (q + 1) + (x - r) * q) + i;
}

// ---------------- zero histogram state (out no longer needs zeroing) ----------------
__global__ void zero_kernel(int* __restrict__ cc) {
  cc[threadIdx.x] = 0;   // counts[64] + cursor[64]
}

// ---------------- x fp32 -> bf16 ----------------
__global__ __launch_bounds__(256) void xcast_kernel(const float* __restrict__ x,
                                                    uint16_t* __restrict__ xb) {
  size_t i = ((size_t)blockIdx.x * 256 + threadIdx.x) * 8;
  float4 a = *(const float4*)(x + i);
  float4 b = *(const float4*)(x + i + 4);
  uint4 o;
  o.x = (uint32_t)f2b(a.x) | ((uint32_t)f2b(a.y) << 16);
  o.y = (uint32_t)f2b(a.z) | ((uint32_t)f2b(a.w) << 16);
  o.z = (uint32_t)f2b(b.x) | ((uint32_t)f2b(b.y) << 16);
  o.w = (uint32_t)f2b(b.z) | ((uint32_t)f2b(b.w) << 16);
  *(uint4*)(xb + i) = o;
}

// ---------------- weight prep via LDS transpose ----------------
// fp32 [K][N] -> bf16 [r(n)][K]; 64k x 64n tile per block; coalesced both sides.
// mode 0: r=n ; mode 1: r=((n>>4)<<5)+(n&15) ; mode 2: r=((n>>4)<<5)+16+(n&15)
__global__ __launch_bounds__(256) void wprep_kernel(
    const float* __restrict__ src, uint16_t* __restrict__ dst,
    int K, int N, int R, int mode)
{
  __shared__ uint16_t tile[64][70];   // row stride 35 dwords: n*35 % 32 == n*3 % 32, conflict-free
  const int e  = blockIdx.z;
  const int k0 = blockIdx.x * 64;
  const int n0 = blockIdx.y * 64;
  const int t  = threadIdx.x;
  const int n  = t & 63;
  const int kq = t >> 6;

  const float* sp = src + (size_t)e * K * N + (size_t)k0 * N + n0 + n;
  #pragma unroll
  for (int i = 0; i < 8; ++i) {
    int k = i * 8 + kq * 2;
    float w0 = sp[(size_t)k * N];
    float w1 = sp[(size_t)(k + 1) * N];
    uint32_t pk = (uint32_t)f2b(w0) | ((uint32_t)f2b(w1) << 16);
    *(uint32_t*)&tile[n][k] = pk;
  }
  __syncthreads();

  uint16_t* dp = dst + (size_t)e * R * K;
  #pragma unroll
  for (int pass = 0; pass < 2; ++pass) {
    int rl   = pass * 32 + (t >> 3);
    int seg8 = (t & 7) * 8;
    uint32_t a0 = *(const uint32_t*)&tile[rl][seg8];
    uint32_t a1 = *(const uint32_t*)&tile[rl][seg8 + 2];
    uint32_t a2 = *(const uint32_t*)&tile[rl][seg8 + 4];
    uint32_t a3 = *(const uint32_t*)&tile[rl][seg8 + 6];
    int ng = n0 + rl;
    int r = (mode == 0) ? ng : (((ng >> 4) << 5) + (ng & 15) + ((mode == 2) ? 16 : 0));
    uint4 o = {a0, a1, a2, a3};
    *(uint4*)&dp[(size_t)r * K + k0 + seg8] = o;
  }
}

// ---------------- router: logits + top8 + softmax + histogram ----------------
__global__ __launch_bounds__(256) void router_kernel(
    const float* __restrict__ x, const float* __restrict__ gate_w,
    float* __restrict__ logits, int* __restrict__ topk_id,
    float* __restrict__ topk_w, int* __restrict__ counts)
{
  int lane = threadIdx.x & 63;
  int wv   = threadIdx.x >> 6;
  int t    = blockIdx.x * 4 + wv;
  const float* xr = x + (size_t)t * HID;
  float acc = 0.f;
  #pragma unroll 4
  for (int h = 0; h < HID; h += 4) {
    float4 xv = *(const float4*)(xr + h);
    acc += xv.x * gate_w[(h + 0) * NEXP + lane];
    acc += xv.y * gate_w[(h + 1) * NEXP + lane];
    acc += xv.z * gate_w[(h + 2) * NEXP + lane];
    acc += xv.w * gate_w[(h + 3) * NEXP + lane];
  }
  logits[(size_t)t * NEXP + lane] = acc;

  float v = acc;
  float topv[TOPK]; int topi[TOPK];
  #pragma unroll
  for (int k = 0; k < TOPK; ++k) {
    float bv = v; int bi = lane;
    #pragma unroll
    for (int off = 32; off > 0; off >>= 1) {
      float ov = __shfl_xor(bv, off);
      int   oi = __shfl_xor(bi, off);
      if (ov > bv || (ov == bv && oi < bi)) { bv = ov; bi = oi; }
    }
    topv[k] = bv; topi[k] = bi;
    if (lane == bi) v = -3.0e38f;
  }
  float m = topv[0], s = 0.f, w[TOPK];
  #pragma unroll
  for (int k = 0; k < TOPK; ++k) { w[k] = __expf(topv[k] - m); s += w[k]; }
  float inv = 1.f / s;
  if (lane < TOPK) {
    topk_id[t * TOPK + lane] = topi[lane];
    topk_w[t * TOPK + lane]  = w[lane] * inv;
    atomicAdd(&counts[topi[lane]], 1);
  }
}

// ---------------- offsets + dense tile list ----------------
__global__ void offsets_kernel(const int* __restrict__ counts, int* __restrict__ offsets,
                               int* __restrict__ tiles, int* __restrict__ tilecount) {
  if (threadIdx.x == 0) {
    int s = 0, nt = 0;
    for (int e = 0; e < NEXP; ++e) {
      offsets[e] = s;
      int c = counts[e];
      for (int rb = 0; rb * 128 < c; ++rb) tiles[nt++] = (e << 16) | rb;
      s += c;
    }
    offsets[NEXP] = s;
    tilecount[0] = nt;
  }
}

// ---------------- scatter pairs grouped by expert (+ inverse map) ----------------
__global__ __launch_bounds__(256) void scatter_kernel(
    const int* __restrict__ topk_id,
    const int* __restrict__ offsets, int* __restrict__ cursor,
    int* __restrict__ pair_tok, int* __restrict__ inv)
{
  int p = blockIdx.x * 256 + threadIdx.x;   // pair index = t*8+k
  int e = topk_id[p];
  int pos = offsets[e] + atomicAdd(&cursor[e], 1);
  pair_tok[pos] = p;
  inv[p] = pos;
}

// ================= gate+up grouped GEMM (combined interleaved N=1536) =================
// 1D grid MAXT*12, tile-list driven, XCD-balanced
__global__ __launch_bounds__(256, 2) void gateup_kernel(
    const uint16_t* __restrict__ xb,
    const uint16_t* __restrict__ gu_t,     // [e][1536][2048] bf16, 16-row gate/up interleave
    const int* __restrict__ pair_tok,
    const int* __restrict__ offsets,
    const int* __restrict__ tiles,
    const int* __restrict__ tilecount,
    uint16_t* __restrict__ act)
{
  const int nt = tilecount[0];
  const int na = nt * 12;
  if (blockIdx.x >= na) return;
  const int L  = xcd_unswizzle(blockIdx.x, na);
  const int ti = L % nt, nc = L / nt;
  const int te = tiles[ti];
  const int e = te >> 16, row0 = (te & 0xffff) * 128;
  const int start = offsets[e];
  const int count = offsets[e + 1] - start;
  const int nvalid = min(128, count - row0);

  __shared__ __align__(16) uint16_t aT[128 * 64];
  __shared__ __align__(16) uint16_t bT[128 * 64];
  __shared__ int s_tok[128];

  const int t = threadIdx.x, l = t & 63, w = t >> 6;
  if (t < 128)
    s_tok[t] = (t < nvalid) ? (pair_tok[start + row0 + t] >> 3) : 0;
  __syncthreads();

  const int sub = l >> 3;                       // row-in-8-group
  const int xk  = ((l & 7) ^ sub) << 3;         // swizzled source k-chunk (elements)

  const uint16_t* srcA[4]; const uint16_t* srcB[4];
  char* dstA[4]; char* dstB[4];
  const uint16_t* gub = gu_t + (size_t)e * 1536 * HID;
  #pragma unroll
  for (int q = 0; q < 4; ++q) {
    int rl = (w * 4 + q) * 8 + sub;
    srcA[q] = xb + (size_t)s_tok[rl] * HID + xk;
    srcB[q] = gub + (size_t)(nc * 128 + rl) * HID + xk;
    dstA[q] = (char*)aT + (w * 4 + q) * 1024;
    dstB[q] = (char*)bT + (w * 4 + q) * 1024;
  }

  const int wr = w >> 1, wc = w & 1, lr = l & 15, hi = l >> 4;
  const int xorv = (lr & 7) << 4;               // byte XOR for swizzled read

  f32x4 acc[4][4];
  #pragma unroll
  for (int mi = 0; mi < 4; ++mi)
    #pragma unroll
    for (int ni = 0; ni < 4; ++ni)
      acc[mi][ni] = (f32x4){0.f, 0.f, 0.f, 0.f};

  for (int kc = 0; kc < 32; ++kc) {
    __syncthreads();
    #pragma unroll
    for (int q = 0; q < 4; ++q) {
      gl2lds16(srcA[q] + kc * 64, dstA[q]);
      gl2lds16(srcB[q] + kc * 64, dstB[q]);
    }
    __syncthreads();
    #pragma unroll
    for (int ks = 0; ks < 2; ++ks) {
      sh8 af[4], bf[4];
      #pragma unroll
      for (int mi = 0; mi < 4; ++mi)
        af[mi] = *(const sh8*)((const char*)aT +
                   (wr * 64 + mi * 16 + lr) * 128 + ((ks * 64 + hi * 16) ^ xorv));
      #pragma unroll
      for (int ni = 0; ni < 4; ++ni)
        bf[ni] = *(const sh8*)((const char*)bT +
                   (wc * 64 + ni * 16 + lr) * 128 + ((ks * 64 + hi * 16) ^ xorv));
      #pragma unroll
      for (int mi = 0; mi < 4; ++mi)
        #pragma unroll
        for (int ni = 0; ni < 4; ++ni)
          acc[mi][ni] = MFMA16(af[mi], bf[ni], acc[mi][ni], 0, 0, 0);
    }
  }

  // epilogue: ni even = gate, ni odd = up (same original column) -> silu(g)*u
  #pragma unroll
  for (int mi = 0; mi < 4; ++mi)
    #pragma unroll
    for (int p = 0; p < 2; ++p)
      #pragma unroll
      for (int j = 0; j < 4; ++j) {
        int row = wr * 64 + mi * 16 + hi * 4 + j;
        if (row < nvalid) {
          float g = acc[mi][2 * p][j], u = acc[mi][2 * p + 1][j];
          float a = (g / (1.f + __expf(-g))) * u;
          int col = nc * 64 + wc * 32 + p * 16 + lr;
          act[(size_t)(start + row0 + row) * ITER + col] = f2b(a);
        }
      }
}

// ================= down grouped GEMM -> dense bf16 rows (no atomics) =================
// 1D grid MAXT*16, tile-list driven, XCD-balanced
__global__ __launch_bounds__(256, 2) void down_kernel(
    const uint16_t* __restrict__ act,
    const uint16_t* __restrict__ down_t,   // [e][2048][768] bf16
    const int* __restrict__ offsets,
    const int* __restrict__ tiles,
    const int* __restrict__ tilecount,
    uint16_t* __restrict__ dd)             // [32768][2048] bf16, sorted-pair rows
{
  const int nt = tilecount[0];
  const int na = nt * 16;
  if (blockIdx.x >= na) return;
  const int L  = xcd_unswizzle(blockIdx.x, na);
  const int ti = L % nt, nc = L / nt;
  const int te = tiles[ti];
  const int e = te >> 16, row0 = (te & 0xffff) * 128;
  const int start = offsets[e];
  const int count = offsets[e + 1] - start;
  const int nvalid = min(128, count - row0);

  __shared__ __align__(16) uint16_t aT[128 * 64];
  __shared__ __align__(16) uint16_t bT[128 * 64];

  const int t = threadIdx.x, l = t & 63, w = t >> 6;

  const int sub = l >> 3;
  const int xk  = ((l & 7) ^ sub) << 3;

  const uint16_t* srcA[4]; const uint16_t* srcB[4];
  char* dstA[4]; char* dstB[4];
  const uint16_t* wdb = down_t + (size_t)e * HID * ITER;
  #pragma unroll
  for (int q = 0; q < 4; ++q) {
    int rl = (w * 4 + q) * 8 + sub;
    srcA[q] = act + (size_t)(start + row0 + rl) * ITER + xk;
    srcB[q] = wdb + (size_t)(nc * 128 + rl) * ITER + xk;
    dstA[q] = (char*)aT + (w * 4 + q) * 1024;
    dstB[q] = (char*)bT + (w * 4 + q) * 1024;
  }

  const int wr = w >> 1, wc = w & 1, lr = l & 15, hi = l >> 4;
  const int xorv = (lr & 7) << 4;

  f32x4 acc[4][4];
  #pragma unroll
  for (int mi = 0; mi < 4; ++mi)
    #pragma unroll
    for (int ni = 0; ni < 4; ++ni)
      acc[mi][ni] = (f32x4){0.f, 0.f, 0.f, 0.f};

  for (int kc = 0; kc < 12; ++kc) {
    __syncthreads();
    #pragma unroll
    for (int q = 0; q < 4; ++q) {
      gl2lds16(srcA[q] + kc * 64, dstA[q]);
      gl2lds16(srcB[q] + kc * 64, dstB[q]);
    }
    __syncthreads();
    #pragma unroll
    for (int ks = 0; ks < 2; ++ks) {
      sh8 af[4], bf[4];
      #pragma unroll
      for (int mi = 0; mi < 4; ++mi)
        af[mi] = *(const sh8*)((const char*)aT +
                   (wr * 64 + mi * 16 + lr) * 128 + ((ks * 64 + hi * 16) ^ xorv));
      #pragma unroll
      for (int ni = 0; ni < 4; ++ni)
        bf[ni] = *(const sh8*)((const char*)bT +
                   (wc * 64 + ni * 16 + lr) * 128 + ((ks * 64 + hi * 16) ^ xorv));
      #pragma unroll
      for (int mi = 0; mi < 4; ++mi)
        #pragma unroll
        for (int ni = 0; ni < 4; ++ni)
          acc[mi][ni] = MFMA16(af[mi], bf[ni], acc[mi][ni], 0, 0, 0);
    }
  }

  #pragma unroll
  for (int mi = 0; mi < 4; ++mi)
    #pragma unroll
    for (int ni = 0; ni < 4; ++ni)
      #pragma unroll
      for (int j = 0; j < 4; ++j) {
        int row = wr * 64 + mi * 16 + hi * 4 + j;
        if (row < nvalid) {
          int col = nc * 128 + wc * 64 + ni * 16 + lr;
          dd[(size_t)(start + row0 + row) * HID + col] = f2b(acc[mi][ni][j]);
        }
      }
}

// ================= per-token weighted reduction of 8 expert rows =================
__global__ __launch_bounds__(256) void reduce_kernel(
    const uint16_t* __restrict__ dd, const float* __restrict__ topk_w,
    const int* __restrict__ inv, float* __restrict__ out)
{
  const int tok = blockIdx.x;
  const int c   = threadIdx.x * 8;
  float acc[8] = {0.f, 0.f, 0.f, 0.f, 0.f, 0.f, 0.f, 0.f};
  #pragma unroll
  for (int k = 0; k < TOPK; ++k) {
    const int   pos = inv[tok * TOPK + k];
    const float wk  = topk_w[tok * TOPK + k];
    uint4 v = *(const uint4*)&dd[(size_t)pos * HID + c];
    acc[0] += wk * b2f_lo(v.x);  acc[1] += wk * b2f_hi(v.x);
    acc[2] += wk * b2f_lo(v.y);  acc[3] += wk * b2f_hi(v.y);
    acc[4] += wk * b2f_lo(v.z);  acc[5] += wk * b2f_hi(v.z);
    acc[6] += wk * b2f_lo(v.w);  acc[7] += wk * b2f_hi(v.w);
  }
  float4 o0 = {acc[0], acc[1], acc[2], acc[3]};
  float4 o1 = {acc[4], acc[5], acc[6], acc[7]};
  float* op = out + (size_t)tok * HID + c;
  *(float4*)op       = o0;
  *(float4*)(op + 4) = o1;
}

extern "C" void kernel_launch(void* const* d_in, const int* in_sizes, int n_in,
                              void* d_out, int out_size, void* d_ws, size_t ws_size,
                              hipStream_t stream) {
  const float* x         = (const float*)d_in[0];
  const float* gate_w    = (const float*)d_in[1];
  const float* gate_proj = (const float*)d_in[2];
  const float* up_proj   = (const float*)d_in[3];
  const float* down_proj = (const float*)d_in[4];

  float* out    = (float*)d_out;                     // [4096, 2048]
  float* logits = out + (size_t)NTOK * HID;          // [4096, 64]

  // workspace layout (~672 MB total); dd aliases gu_t (dead after gateup)
  char* ws = (char*)d_ws;
  size_t off = 0;
  uint16_t* xb      = (uint16_t*)(ws + off); off += (size_t)NTOK * HID * 2;            // 16.8 MB
  uint16_t* gu_t    = (uint16_t*)(ws + off); off += (size_t)NEXP * 1536 * HID * 2;     // 402.7 MB
  uint16_t* down_t  = (uint16_t*)(ws + off); off += (size_t)NEXP * HID * ITER * 2;     // 201.3 MB
  uint16_t* act     = (uint16_t*)(ws + off); off += (size_t)(NTOK * TOPK + 128) * ITER * 2; // 50.5 MB
  int*      topk_id = (int*)  (ws + off); off += (size_t)NTOK * TOPK * 4;
  float*    topk_w  = (float*)(ws + off); off += (size_t)NTOK * TOPK * 4;
  int*      counts  = (int*)  (ws + off); off += 256;
  int*      cursor  = (int*)  (ws + off); off += 256;
  int*      offsets = (int*)  (ws + off); off += 512;
  int*      tiles   = (int*)  (ws + off); off += MAXT * 4;
  int*      tilecount=(int*)  (ws + off); off += 256;
  int*      pair_tok= (int*)  (ws + off); off += (size_t)NTOK * TOPK * 4;
  int*      inv     = (int*)  (ws + off); off += (size_t)NTOK * TOPK * 4;
  uint16_t* dd      = gu_t;                          // [32768][2048] bf16, 134 MB alias

  zero_kernel   <<<1,    128, 0, stream>>>(counts);
  xcast_kernel  <<<4096, 256, 0, stream>>>(x, xb);
  router_kernel <<<1024, 256, 0, stream>>>(x, gate_w, logits, topk_id, topk_w, counts);
  offsets_kernel<<<1,    64,  0, stream>>>(counts, offsets, tiles, tilecount);
  scatter_kernel<<<128,  256, 0, stream>>>(topk_id, offsets, cursor, pair_tok, inv);

  // weight prep: fp32 [K][N] -> bf16 [n][K] (gate/up interleaved into gu_t)
  wprep_kernel<<<dim3(32, 12, 64), 256, 0, stream>>>(gate_proj, gu_t,   HID,  ITER, 1536, 1);
  wprep_kernel<<<dim3(32, 12, 64), 256, 0, stream>>>(up_proj,   gu_t,   HID,  ITER, 1536, 2);
  wprep_kernel<<<dim3(12, 32, 64), 256, 0, stream>>>(down_proj, down_t, ITER, HID,  HID,  0);

  gateup_kernel<<<MAXT * 12, 256, 0, stream>>>(xb, gu_t, pair_tok, offsets,
                                               tiles, tilecount, act);
  down_kernel  <<<MAXT * 16, 256, 0, stream>>>(act, down_t, offsets,
                                               tiles, tilecount, dd);
  reduce_kernel<<<NTOK, 256, 0, stream>>>(dd, topk_w, inv, out);
}

// Round 6
// 940.868 us; speedup vs baseline: 8.5699x; 1.1289x over previous
//
#include <hip/hip_runtime.h>
#include <hip/hip_bf16.h>
#include <cstdint>

#define NTOK 4096
#define HID  2048
#define ITER 768
#define NEXP 64
#define TOPK 8
#define MAXT 320   // max row-tiles: 32768/128 + 63 padding tiles

typedef __attribute__((ext_vector_type(8))) short sh8;
typedef __attribute__((ext_vector_type(4))) float f32x4;

#define MFMA16 __builtin_amdgcn_mfma_f32_16x16x32_bf16

__device__ __forceinline__ uint16_t f2b(float f) {
  union { float f; uint32_t u; } v; v.f = f;
  uint32_t u = v.u;
  u += 0x7FFFu + ((u >> 16) & 1u);   // RNE
  return (uint16_t)(u >> 16);
}

__device__ __forceinline__ float b2f_lo(uint32_t w) {   // bf16 in bits[15:0]
  union { uint32_t u; float f; } v; v.u = w << 16; return v.f;
}
__device__ __forceinline__ float b2f_hi(uint32_t w) {   // bf16 in bits[31:16]
  union { uint32_t u; float f; } v; v.u = w & 0xffff0000u; return v.f;
}

__device__ __forceinline__ uint32_t cvtpk(float lo, float hi) {
  float2 f2; f2.x = lo; f2.y = hi;
  __hip_bfloat162 h = __float22bfloat162_rn(f2);
  union { __hip_bfloat162 h; uint32_t u; } v; v.h = h;
  return v.u;
}

__device__ __forceinline__ void gl2lds16(const void* g, void* l) {
  __builtin_amdgcn_global_load_lds(
      (const __attribute__((address_space(1))) uint32_t*)g,
      (__attribute__((address_space(3))) uint32_t*)l, 16, 0, 0);
}

// m204 bijective XCD-chunked swizzle: hw slot s -> logical L (contiguous L per XCD)
__device__ __forceinline__ int xcd_unswizzle(int s, int na) {
  int q = na >> 3, r = na & 7, x = s & 7, i = s >> 3;
  return (x < r ? x * (q + 1) : r * (q + 1) + (x - r) * q) + i;
}

// ---------------- zero histogram state ----------------
__global__ void zero_kernel(int* __restrict__ cc) {
  cc[threadIdx.x] = 0;   // counts[64] + cursor[64]
}

// ---------------- x fp32 -> bf16 ----------------
__global__ __launch_bounds__(256) void xcast_kernel(const float* __restrict__ x,
                                                    uint16_t* __restrict__ xb) {
  size_t i = ((size_t)blockIdx.x * 256 + threadIdx.x) * 8;
  float4 a = *(const float4*)(x + i);
  float4 b = *(const float4*)(x + i + 4);
  uint4 o;
  o.x = (uint32_t)f2b(a.x) | ((uint32_t)f2b(a.y) << 16);
  o.y = (uint32_t)f2b(a.z) | ((uint32_t)f2b(a.w) << 16);
  o.z = (uint32_t)f2b(b.x) | ((uint32_t)f2b(b.y) << 16);
  o.w = (uint32_t)f2b(b.z) | ((uint32_t)f2b(b.w) << 16);
  *(uint4*)(xb + i) = o;
}

// ---------------- router: logits + top8 + softmax + histogram ----------------
__global__ __launch_bounds__(256) void router_kernel(
    const float* __restrict__ x, const float* __restrict__ gate_w,
    float* __restrict__ logits, int* __restrict__ topk_id,
    float* __restrict__ topk_w, int* __restrict__ counts)
{
  int lane = threadIdx.x & 63;
  int wv   = threadIdx.x >> 6;
  int t    = blockIdx.x * 4 + wv;
  const float* xr = x + (size_t)t * HID;
  float acc = 0.f;
  #pragma unroll 4
  for (int h = 0; h < HID; h += 4) {
    float4 xv = *(const float4*)(xr + h);
    acc += xv.x * gate_w[(h + 0) * NEXP + lane];
    acc += xv.y * gate_w[(h + 1) * NEXP + lane];
    acc += xv.z * gate_w[(h + 2) * NEXP + lane];
    acc += xv.w * gate_w[(h + 3) * NEXP + lane];
  }
  logits[(size_t)t * NEXP + lane] = acc;

  float v = acc;
  float topv[TOPK]; int topi[TOPK];
  #pragma unroll
  for (int k = 0; k < TOPK; ++k) {
    float bv = v; int bi = lane;
    #pragma unroll
    for (int off = 32; off > 0; off >>= 1) {
      float ov = __shfl_xor(bv, off);
      int   oi = __shfl_xor(bi, off);
      if (ov > bv || (ov == bv && oi < bi)) { bv = ov; bi = oi; }
    }
    topv[k] = bv; topi[k] = bi;
    if (lane == bi) v = -3.0e38f;
  }
  float m = topv[0], s = 0.f, w[TOPK];
  #pragma unroll
  for (int k = 0; k < TOPK; ++k) { w[k] = __expf(topv[k] - m); s += w[k]; }
  float inv = 1.f / s;
  if (lane < TOPK) {
    topk_id[t * TOPK + lane] = topi[lane];
    topk_w[t * TOPK + lane]  = w[lane] * inv;
    atomicAdd(&counts[topi[lane]], 1);
  }
}

// ---------------- offsets + dense tile list ----------------
__global__ void offsets_kernel(const int* __restrict__ counts, int* __restrict__ offsets,
                               int* __restrict__ tiles, int* __restrict__ tilecount) {
  if (threadIdx.x == 0) {
    int s = 0, nt = 0;
    for (int e = 0; e < NEXP; ++e) {
      offsets[e] = s;
      int c = counts[e];
      for (int rb = 0; rb * 128 < c; ++rb) tiles[nt++] = (e << 16) | rb;
      s += c;
    }
    offsets[NEXP] = s;
    tilecount[0] = nt;
  }
}

// ---------------- scatter pairs grouped by expert (+ inverse map) ----------------
__global__ __launch_bounds__(256) void scatter_kernel(
    const int* __restrict__ topk_id,
    const int* __restrict__ offsets, int* __restrict__ cursor,
    int* __restrict__ pair_tok, int* __restrict__ inv)
{
  int p = blockIdx.x * 256 + threadIdx.x;   // pair index = t*8+k
  int e = topk_id[p];
  int pos = offsets[e] + atomicAdd(&cursor[e], 1);
  pair_tok[pos] = p;
  inv[p] = pos;
}

// ================= gate+up grouped GEMM, fused fp32->bf16 B conversion =================
// 1D grid MAXT*12, tile-list driven, XCD-balanced. B read directly from fp32
// weights [k][n]: per-thread 32 lane-coalesced scalar loads -> cvt_pk -> swizzled
// ds_write_b128 (same involution as the ds_read side). Sibling row-tiles of one
// (e,nc) are L-adjacent -> same XCD -> fp32 panel (1 MB) is L2-served after first.
__global__ __launch_bounds__(256, 2) void gateup_kernel(
    const uint16_t* __restrict__ xb,
    const float* __restrict__ gate_proj,
    const float* __restrict__ up_proj,
    const int* __restrict__ pair_tok,
    const int* __restrict__ offsets,
    const int* __restrict__ tiles,
    const int* __restrict__ tilecount,
    uint16_t* __restrict__ act)
{
  const int nt = tilecount[0];
  const int na = nt * 12;
  if (blockIdx.x >= na) return;
  const int L  = xcd_unswizzle(blockIdx.x, na);
  const int ti = L % nt, nc = L / nt;
  const int te = tiles[ti];
  const int e = te >> 16, row0 = (te & 0xffff) * 128;
  const int start = offsets[e];
  const int count = offsets[e + 1] - start;
  const int nvalid = min(128, count - row0);

  __shared__ __align__(16) uint16_t aT[128 * 64];
  __shared__ __align__(16) uint16_t bT[128 * 64];
  __shared__ int s_tok[128];

  const int t = threadIdx.x, l = t & 63, w = t >> 6;
  if (t < 128)
    s_tok[t] = (t < nvalid) ? (pair_tok[start + row0 + t] >> 3) : 0;
  __syncthreads();

  // A staging (gl2lds, pre-swizzled per-lane source)
  const int sub = l >> 3;
  const int xk  = ((l & 7) ^ sub) << 3;
  const uint16_t* srcA[4]; char* dstA[4];
  #pragma unroll
  for (int q = 0; q < 4; ++q) {
    int rl = (w * 4 + q) * 8 + sub;
    srcA[q] = xb + (size_t)s_tok[rl] * HID + xk;
    dstA[q] = (char*)aT + (w * 4 + q) * 1024;
  }

  // B reg-staging: thread -> bT row brow, k-half kk0 (32 of 64 k per step)
  const int brow = t & 127;
  const int kk0  = (t >> 7) * 32;
  const int rcomb  = nc * 128 + brow;                    // combined interleaved col
  const int n_orig = ((rcomb >> 5) << 4) + (rcomb & 15); // orig col in [0,768)
  const int is_up  = (rcomb >> 4) & 1;
  const float* wsrc = (is_up ? up_proj : gate_proj)
                    + (size_t)e * HID * ITER + n_orig;   // [k][n] fp32, ldw=ITER
  uint16_t* bwr[4];
  #pragma unroll
  for (int s = 0; s < 4; ++s) {
    int kb = (kk0 * 2 + 16 * s) ^ ((brow & 7) << 4);
    bwr[s] = (uint16_t*)((char*)bT + brow * 128 + kb);
  }

  const int wr = w >> 1, wc = w & 1, lr = l & 15, hi = l >> 4;
  const int xorv = (lr & 7) << 4;

  f32x4 acc[4][4];
  #pragma unroll
  for (int mi = 0; mi < 4; ++mi)
    #pragma unroll
    for (int ni = 0; ni < 4; ++ni)
      acc[mi][ni] = (f32x4){0.f, 0.f, 0.f, 0.f};

  for (int kc = 0; kc < 32; ++kc) {
    __syncthreads();
    // issue B fp32 loads (lane-coalesced 256B rows), then A gl2lds
    float va[32];
    const float* wp = wsrc + (size_t)(kc * 64 + kk0) * ITER;
    #pragma unroll
    for (int j = 0; j < 32; ++j) va[j] = wp[(size_t)j * ITER];
    #pragma unroll
    for (int q = 0; q < 4; ++q)
      gl2lds16(srcA[q] + kc * 64, dstA[q]);
    // convert + swizzled LDS write
    #pragma unroll
    for (int s = 0; s < 4; ++s) {
      uint4 o;
      o.x = cvtpk(va[s * 8 + 0], va[s * 8 + 1]);
      o.y = cvtpk(va[s * 8 + 2], va[s * 8 + 3]);
      o.z = cvtpk(va[s * 8 + 4], va[s * 8 + 5]);
      o.w = cvtpk(va[s * 8 + 6], va[s * 8 + 7]);
      *(uint4*)bwr[s] = o;
    }
    __syncthreads();
    #pragma unroll
    for (int ks = 0; ks < 2; ++ks) {
      sh8 af[4], bf[4];
      #pragma unroll
      for (int mi = 0; mi < 4; ++mi)
        af[mi] = *(const sh8*)((const char*)aT +
                   (wr * 64 + mi * 16 + lr) * 128 + ((ks * 64 + hi * 16) ^ xorv));
      #pragma unroll
      for (int ni = 0; ni < 4; ++ni)
        bf[ni] = *(const sh8*)((const char*)bT +
                   (wc * 64 + ni * 16 + lr) * 128 + ((ks * 64 + hi * 16) ^ xorv));
      #pragma unroll
      for (int mi = 0; mi < 4; ++mi)
        #pragma unroll
        for (int ni = 0; ni < 4; ++ni)
          acc[mi][ni] = MFMA16(af[mi], bf[ni], acc[mi][ni], 0, 0, 0);
    }
  }

  // epilogue: ni even = gate, ni odd = up (same original column) -> silu(g)*u
  #pragma unroll
  for (int mi = 0; mi < 4; ++mi)
    #pragma unroll
    for (int p = 0; p < 2; ++p)
      #pragma unroll
      for (int j = 0; j < 4; ++j) {
        int row = wr * 64 + mi * 16 + hi * 4 + j;
        if (row < nvalid) {
          float g = acc[mi][2 * p][j], u = acc[mi][2 * p + 1][j];
          float a = (g / (1.f + __expf(-g))) * u;
          int col = nc * 64 + wc * 32 + p * 16 + lr;
          act[(size_t)(start + row0 + row) * ITER + col] = f2b(a);
        }
      }
}

// ================= down grouped GEMM, fused fp32->bf16 B, dense bf16 out =================
// 1D grid MAXT*16, tile-list driven, XCD-balanced
__global__ __launch_bounds__(256, 2) void down_kernel(
    const uint16_t* __restrict__ act,
    const float* __restrict__ down_proj,   // [e][768 k][2048 n] fp32
    const int* __restrict__ offsets,
    const int* __restrict__ tiles,
    const int* __restrict__ tilecount,
    uint16_t* __restrict__ dd)             // [32768][2048] bf16, sorted-pair rows
{
  const int nt = tilecount[0];
  const int na = nt * 16;
  if (blockIdx.x >= na) return;
  const int L  = xcd_unswizzle(blockIdx.x, na);
  const int ti = L % nt, nc = L / nt;
  const int te = tiles[ti];
  const int e = te >> 16, row0 = (te & 0xffff) * 128;
  const int start = offsets[e];
  const int count = offsets[e + 1] - start;
  const int nvalid = min(128, count - row0);

  __shared__ __align__(16) uint16_t aT[128 * 64];
  __shared__ __align__(16) uint16_t bT[128 * 64];

  const int t = threadIdx.x, l = t & 63, w = t >> 6;

  const int sub = l >> 3;
  const int xk  = ((l & 7) ^ sub) << 3;

  const uint16_t* srcA[4]; char* dstA[4];
  #pragma unroll
  for (int q = 0; q < 4; ++q) {
    int rl = (w * 4 + q) * 8 + sub;
    srcA[q] = act + (size_t)(start + row0 + rl) * ITER + xk;
    dstA[q] = (char*)aT + (w * 4 + q) * 1024;
  }

  const int brow = t & 127;
  const int kk0  = (t >> 7) * 32;
  const float* wsrc = down_proj + (size_t)e * ITER * HID + nc * 128 + brow; // ldw=HID
  uint16_t* bwr[4];
  #pragma unroll
  for (int s = 0; s < 4; ++s) {
    int kb = (kk0 * 2 + 16 * s) ^ ((brow & 7) << 4);
    bwr[s] = (uint16_t*)((char*)bT + brow * 128 + kb);
  }

  const int wr = w >> 1, wc = w & 1, lr = l & 15, hi = l >> 4;
  const int xorv = (lr & 7) << 4;

  f32x4 acc[4][4];
  #pragma unroll
  for (int mi = 0; mi < 4; ++mi)
    #pragma unroll
    for (int ni = 0; ni < 4; ++ni)
      acc[mi][ni] = (f32x4){0.f, 0.f, 0.f, 0.f};

  for (int kc = 0; kc < 12; ++kc) {
    __syncthreads();
    float va[32];
    const float* wp = wsrc + (size_t)(kc * 64 + kk0) * HID;
    #pragma unroll
    for (int j = 0; j < 32; ++j) va[j] = wp[(size_t)j * HID];
    #pragma unroll
    for (int q = 0; q < 4; ++q)
      gl2lds16(srcA[q] + kc * 64, dstA[q]);
    #pragma unroll
    for (int s = 0; s < 4; ++s) {
      uint4 o;
      o.x = cvtpk(va[s * 8 + 0], va[s * 8 + 1]);
      o.y = cvtpk(va[s * 8 + 2], va[s * 8 + 3]);
      o.z = cvtpk(va[s * 8 + 4], va[s * 8 + 5]);
      o.w = cvtpk(va[s * 8 + 6], va[s * 8 + 7]);
      *(uint4*)bwr[s] = o;
    }
    __syncthreads();
    #pragma unroll
    for (int ks = 0; ks < 2; ++ks) {
      sh8 af[4], bf[4];
      #pragma unroll
      for (int mi = 0; mi < 4; ++mi)
        af[mi] = *(const sh8*)((const char*)aT +
                   (wr * 64 + mi * 16 + lr) * 128 + ((ks * 64 + hi * 16) ^ xorv));
      #pragma unroll
      for (int ni = 0; ni < 4; ++ni)
        bf[ni] = *(const sh8*)((const char*)bT +
                   (wc * 64 + ni * 16 + lr) * 128 + ((ks * 64 + hi * 16) ^ xorv));
      #pragma unroll
      for (int mi = 0; mi < 4; ++mi)
        #pragma unroll
        for (int ni = 0; ni < 4; ++ni)
          acc[mi][ni] = MFMA16(af[mi], bf[ni], acc[mi][ni], 0, 0, 0);
    }
  }

  #pragma unroll
  for (int mi = 0; mi < 4; ++mi)
    #pragma unroll
    for (int ni = 0; ni < 4; ++ni)
      #pragma unroll
      for (int j = 0; j < 4; ++j) {
        int row = wr * 64 + mi * 16 + hi * 4 + j;
        if (row < nvalid) {
          int col = nc * 128 + wc * 64 + ni * 16 + lr;
          dd[(size_t)(start + row0 + row) * HID + col] = f2b(acc[mi][ni][j]);
        }
      }
}

// ================= per-token weighted reduction of 8 expert rows =================
__global__ __launch_bounds__(256) void reduce_kernel(
    const uint16_t* __restrict__ dd, const float* __restrict__ topk_w,
    const int* __restrict__ inv, float* __restrict__ out)
{
  const int tok = blockIdx.x;
  const int c   = threadIdx.x * 8;
  float acc[8] = {0.f, 0.f, 0.f, 0.f, 0.f, 0.f, 0.f, 0.f};
  #pragma unroll
  for (int k = 0; k < TOPK; ++k) {
    const int   pos = inv[tok * TOPK + k];
    const float wk  = topk_w[tok * TOPK + k];
    uint4 v = *(const uint4*)&dd[(size_t)pos * HID + c];
    acc[0] += wk * b2f_lo(v.x);  acc[1] += wk * b2f_hi(v.x);
    acc[2] += wk * b2f_lo(v.y);  acc[3] += wk * b2f_hi(v.y);
    acc[4] += wk * b2f_lo(v.z);  acc[5] += wk * b2f_hi(v.z);
    acc[6] += wk * b2f_lo(v.w);  acc[7] += wk * b2f_hi(v.w);
  }
  float4 o0 = {acc[0], acc[1], acc[2], acc[3]};
  float4 o1 = {acc[4], acc[5], acc[6], acc[7]};
  float* op = out + (size_t)tok * HID + c;
  *(float4*)op       = o0;
  *(float4*)(op + 4) = o1;
}

extern "C" void kernel_launch(void* const* d_in, const int* in_sizes, int n_in,
                              void* d_out, int out_size, void* d_ws, size_t ws_size,
                              hipStream_t stream) {
  const float* x         = (const float*)d_in[0];
  const float* gate_w    = (const float*)d_in[1];
  const float* gate_proj = (const float*)d_in[2];
  const float* up_proj   = (const float*)d_in[3];
  const float* down_proj = (const float*)d_in[4];

  float* out    = (float*)d_out;                     // [4096, 2048]
  float* logits = out + (size_t)NTOK * HID;          // [4096, 64]

  // workspace layout (~205 MB total)
  char* ws = (char*)d_ws;
  size_t off = 0;
  uint16_t* xb      = (uint16_t*)(ws + off); off += (size_t)NTOK * HID * 2;                  // 16.8 MB
  uint16_t* act     = (uint16_t*)(ws + off); off += (size_t)(NTOK * TOPK + 128) * ITER * 2;  // 50.5 MB
  uint16_t* dd      = (uint16_t*)(ws + off); off += (size_t)(NTOK * TOPK + 128) * HID * 2;   // 134.7 MB
  int*      topk_id = (int*)  (ws + off); off += (size_t)NTOK * TOPK * 4;
  float*    topk_w  = (float*)(ws + off); off += (size_t)NTOK * TOPK * 4;
  int*      counts  = (int*)  (ws + off); off += 256;
  int*      cursor  = (int*)  (ws + off); off += 256;
  int*      offsets = (int*)  (ws + off); off += 512;
  int*      tiles   = (int*)  (ws + off); off += MAXT * 4;
  int*      tilecount=(int*)  (ws + off); off += 256;
  int*      pair_tok= (int*)  (ws + off); off += (size_t)NTOK * TOPK * 4;
  int*      inv     = (int*)  (ws + off); off += (size_t)NTOK * TOPK * 4;

  zero_kernel   <<<1,    128, 0, stream>>>(counts);
  xcast_kernel  <<<4096, 256, 0, stream>>>(x, xb);
  router_kernel <<<1024, 256, 0, stream>>>(x, gate_w, logits, topk_id, topk_w, counts);
  offsets_kernel<<<1,    64,  0, stream>>>(counts, offsets, tiles, tilecount);
  scatter_kernel<<<128,  256, 0, stream>>>(topk_id, offsets, cursor, pair_tok, inv);

  gateup_kernel<<<MAXT * 12, 256, 0, stream>>>(xb, gate_proj, up_proj, pair_tok, offsets,
                                               tiles, tilecount, act);
  down_kernel  <<<MAXT * 16, 256, 0, stream>>>(act, down_proj, offsets,
                                               tiles, tilecount, dd);
  reduce_kernel<<<NTOK, 256, 0, stream>>>(dd, topk_w, inv, out);
}